// Round 16
// baseline (98.235 us; speedup 1.0000x reference)
//
#include <hip/hip_runtime.h>
#include <math.h>

using f32x4  = __attribute__((ext_vector_type(4))) float;
using bf16x8 = __attribute__((ext_vector_type(8))) short;

constexpr int kB = 4, kC = 256, kL = 2048, kH = 8;
constexpr float kQScale = 0.25505402264f;  // 1/sqrt(32) * log2(e)

__device__ __forceinline__ unsigned short f2bf(float f) {
    unsigned u = __builtin_bit_cast(unsigned, f);
    u += 0x7fffu + ((u >> 16) & 1u);
    return (unsigned short)(u >> 16);
}
__device__ __forceinline__ unsigned cvt_pk(float lo, float hi) {
    unsigned r;
    asm("v_cvt_pk_bf16_f32 %0, %1, %2" : "=v"(r) : "v"(lo), "v"(hi));
    return r;
}
__device__ __forceinline__ f32x4 mfma16(bf16x8 a, bf16x8 b, f32x4 c) {
    return __builtin_amdgcn_mfma_f32_16x16x32_bf16(a, b, c, 0, 0, 0);
}
__device__ __forceinline__ bf16x8 bc8(unsigned a, unsigned b, unsigned c, unsigned d) {
    return __builtin_bit_cast(bf16x8, make_uint4(a, b, c, d));
}
// async global->LDS, 16B per lane; LDS dest = base + lane*16 (HW-linear).
__device__ __forceinline__ void glds16(const unsigned short* g, unsigned short* l) {
    __builtin_amdgcn_global_load_lds(
        (const __attribute__((address_space(1))) unsigned int*)g,
        (__attribute__((address_space(3))) unsigned int*)l, 16, 0, 0);
}

// ---------------------------------------------------------------------------
// Fused GN (blocks 0..127) + weight cvt (blocks 128..383): one launch stage.
// ---------------------------------------------------------------------------
__global__ __launch_bounds__(256) void gncvt_kernel(const float* __restrict__ x,
                                                    const float* __restrict__ gw,
                                                    const float* __restrict__ gb,
                                                    unsigned short* __restrict__ hT,
                                                    const float* __restrict__ qkvw,
                                                    const float* __restrict__ outw,
                                                    unsigned short* __restrict__ wq,
                                                    unsigned short* __restrict__ wo) {
    if (blockIdx.x >= 128) {  // ---- cvt role ----
        int i = (blockIdx.x - 128) * 256 + threadIdx.x;  // 0..65535 float4s
        const float* s; unsigned short* d; int j;
        if (i < 49152) { s = qkvw; d = wq; j = i; }
        else           { s = outw; d = wo; j = i - 49152; }
        float4 v = ((const float4*)s)[j];
        ((uint2*)d)[j] = make_uint2(cvt_pk(v.x, v.y), cvt_pk(v.z, v.w));
        return;
    }
    // ---- groupnorm role ----
    int b = blockIdx.x >> 5, g = blockIdx.x & 31;
    int t = threadIdx.x;
    const float* xp = x + ((size_t)b * kC + g * 8) * kL + 8 * t;

    float v[8][8];
    float s = 0.f, ss = 0.f;
#pragma unroll
    for (int c = 0; c < 8; ++c) {
        float4 a  = *(const float4*)(xp + (size_t)c * kL);
        float4 a2 = *(const float4*)(xp + (size_t)c * kL + 4);
        v[c][0]=a.x; v[c][1]=a.y; v[c][2]=a.z; v[c][3]=a.w;
        v[c][4]=a2.x; v[c][5]=a2.y; v[c][6]=a2.z; v[c][7]=a2.w;
        s  += (a.x+a.y)+(a.z+a.w)+(a2.x+a2.y)+(a2.z+a2.w);
        ss += a.x*a.x+a.y*a.y+a.z*a.z+a.w*a.w+a2.x*a2.x+a2.y*a2.y+a2.z*a2.z+a2.w*a2.w;
    }
#pragma unroll
    for (int off = 32; off; off >>= 1) {
        s  += __shfl_down(s, off);
        ss += __shfl_down(ss, off);
    }
    __shared__ float red[8];
    int wv = t >> 6;
    if ((t & 63) == 0) { red[wv] = s; red[4 + wv] = ss; }
    __syncthreads();
    s  = red[0] + red[1] + red[2] + red[3];
    ss = red[4] + red[5] + red[6] + red[7];
    float mean = s * (1.f / 16384.f);
    float var  = ss * (1.f / 16384.f) - mean * mean;
    float rstd = rsqrtf(var + 1e-5f);

    float wc[8], bc[8];
#pragma unroll
    for (int c = 0; c < 8; ++c) { wc[c] = gw[g*8+c] * rstd; bc[c] = gb[g*8+c]; }

    unsigned short* hp = hT + ((size_t)b * kL + 8 * t) * kC + g * 8;
#pragma unroll
    for (int j = 0; j < 8; ++j) {
        unsigned pk[4];
#pragma unroll
        for (int c2 = 0; c2 < 4; ++c2) {
            pk[c2] = cvt_pk((v[2*c2  ][j] - mean) * wc[2*c2  ] + bc[2*c2  ],
                            (v[2*c2+1][j] - mean) * wc[2*c2+1] + bc[2*c2+1]);
        }
        *(uint4*)(hp + (size_t)j * kC) = make_uint4(pk[0], pk[1], pk[2], pk[3]);
    }
}

// ---------------------------------------------------------------------------
// Merged QKV GEMM, W-in-registers. Block: o-tile 64 (wave=16 rows), n-tile 128.
// q,k stored transposed [B][H][L][32]; v stored [B][256][L].
// q pre-scaled by 1/sqrt(D)*log2(e), bias fused.
// ---------------------------------------------------------------------------
__device__ __forceinline__ void store_qk(unsigned short* __restrict__ base, size_t bh,
                                         int n, int d0, f32x4 acc,
                                         const float* bias4, float scale) {
    float v0 = (acc[0] + bias4[0]) * scale, v1 = (acc[1] + bias4[1]) * scale;
    float v2 = (acc[2] + bias4[2]) * scale, v3 = (acc[3] + bias4[3]) * scale;
    *(uint2*)(base + (bh * kL + n) * 32 + d0) = make_uint2(cvt_pk(v0, v1), cvt_pk(v2, v3));
}

__global__ __launch_bounds__(256) void qkv_gemm(const unsigned short* __restrict__ Wb,
                                                const unsigned short* __restrict__ hT,
                                                const float* __restrict__ qkvb,
                                                unsigned short* __restrict__ qT,
                                                unsigned short* __restrict__ kT,
                                                unsigned short* __restrict__ vbuf) {
    int t = threadIdx.x, wv = t >> 6, ll = t & 15, lg = (t >> 4) & 3;
    int n0 = blockIdx.x * 128, o0 = blockIdx.y * 64, b = blockIdx.z;
    int obase = o0 + wv * 16;
    const unsigned short* hb = hT + (size_t)b * kL * kC;

    bf16x8 wf[8];
#pragma unroll
    for (int k = 0; k < 8; ++k)
        wf[k] = *(const bf16x8*)(Wb + (size_t)(obase + ll) * 256 + 32 * k + 8 * lg);
    float bias[4];
#pragma unroll
    for (int r = 0; r < 4; ++r) bias[r] = qkvb[obase + 4 * lg + r];
    int mode = (obase < 256) ? 0 : (obase < 512 ? 1 : 2);
    int d0 = (obase & 31) + 4 * lg;

    for (int np = 0; np < 4; ++np) {
        f32x4 acc0 = {}, acc1 = {};
        int nA = n0 + np * 32 + ll, nB = nA + 16;
#pragma unroll
        for (int k = 0; k < 8; ++k) {
            bf16x8 h0 = *(const bf16x8*)(hb + (size_t)nA * 256 + 32 * k + 8 * lg);
            bf16x8 h1 = *(const bf16x8*)(hb + (size_t)nB * 256 + 32 * k + 8 * lg);
            acc0 = mfma16(wf[k], h0, acc0);
            acc1 = mfma16(wf[k], h1, acc1);
        }
        if (mode == 0) {
            size_t bh = (size_t)b * kH + (obase >> 5);
            store_qk(qT, bh, nA, d0, acc0, bias, kQScale);
            store_qk(qT, bh, nB, d0, acc1, bias, kQScale);
        } else if (mode == 1) {
            size_t bh = (size_t)b * kH + ((obase - 256) >> 5);
            store_qk(kT, bh, nA, d0, acc0, bias, 1.f);
            store_qk(kT, bh, nB, d0, acc1, bias, 1.f);
        } else {
#pragma unroll
            for (int r = 0; r < 4; ++r) {
                size_t row = (size_t)b * kC + (obase - 512) + 4 * lg + r;
                vbuf[row * kL + nA] = f2bf(acc0[r] + bias[r]);
                vbuf[row * kL + nB] = f2bf(acc1[r] + bias[r]);
            }
        }
    }
}

// ---------------------------------------------------------------------------
// Flash attention v16 = r14 kernel (best attn, 45.3us) + split-K x2 across
// blocks: each block runs the r14 loop over HALF the keys (16 iters).
// Grid 1024 = exactly 4 blocks/CU x 256 CU (LDS 33.8KB x4 = 135KB < 160KB):
// no tail, 16 waves/CU. Halves combine by plain addition via the r12-validated
// global combine (no-max softmax => addition exact; absmax 0.03125 in r12).
// Wave body, staging, Plds stride-34 transpose, lsum order: r14 VERBATIM.
// ---------------------------------------------------------------------------
__global__ __launch_bounds__(256) void attn_kernel(const unsigned short* __restrict__ qT,
                                                   const unsigned short* __restrict__ kT,
                                                   const unsigned short* __restrict__ vbuf,
                                                   float* __restrict__ pacc,
                                                   float* __restrict__ plsum) {
    __shared__ alignas(16) unsigned short Klds[2][4][512];  // [buf][mj][frag order]
    __shared__ alignas(16) unsigned short Vlds[2][4][512];  // [buf][dj*2+tt][frag]
    __shared__ unsigned Plds[4][32][34];
    int t = threadIdx.x, wv = t >> 6, ll = t & 15, hi = (t >> 4) & 3;
    int lane = t & 63;
    int j = blockIdx.x;
    int bid = (j & 7) * 128 + (j >> 3);   // XCD swizzle: 1024 = 8 x 128, bijective
    int kh = bid & 1;                     // key half
    int qg = (bid >> 1) & 15;             // 128-q group
    int bh = bid >> 5;                    // bh 0..31
    int b = bh >> 3, h = bh & 7;
    const unsigned short* qb = qT + (size_t)bh * kL * 32;
    const unsigned short* kb = kT + (size_t)bh * kL * 32;
    const unsigned short* vb = vbuf + ((size_t)b * kC + h * 32) * kL;
    int nbase = qg * 128 + wv * 32;       // this wave's 32 queries
    int kstart = kh * 1024;               // this block's key half

    bf16x8 qf[2];
#pragma unroll
    for (int nj = 0; nj < 2; ++nj)
        qf[nj] = *(const bf16x8*)(qb + (size_t)(nbase + 16 * nj + ll) * 32 + 8 * hi);

    f32x4 acc[2][2] = {};                 // [nj][dj]
    float lsum[2] = {0.f, 0.f};
    const f32x4 zero = {0.f, 0.f, 0.f, 0.f};

    // per-lane global source offsets (r14 assignments, shifted by kstart):
    const unsigned short* ksrc = kb + (size_t)(kstart + 16 * wv + ll) * 32 + 8 * hi;
    const unsigned short* vsrc = vb + (size_t)(16 * (wv >> 1) + ll) * kL + kstart + 32 * (wv & 1) + 8 * hi;

    // prologue: stage tile 0 into buf 0
    glds16(ksrc, &Klds[0][wv][0]);
    glds16(vsrc, &Vlds[0][wv][0]);
    __syncthreads();

    int cur = 0;
    for (int it = 0; it < 16; ++it) {
        int m0 = it * 64;                 // offset within this block's half
        if (it < 15) {  // stage next tile into the other buffer
            glds16(ksrc + (size_t)(m0 + 64) * 32, &Klds[cur ^ 1][wv][0]);
            glds16(vsrc + m0 + 64,                &Vlds[cur ^ 1][wv][0]);
        }

        // tile-t fragments from LDS (fragment-ordered, conflict-free b128)
        bf16x8 ka[4], va[2][2];
#pragma unroll
        for (int mj = 0; mj < 4; ++mj)
            ka[mj] = *(const bf16x8*)&Klds[cur][mj][lane * 8];
#pragma unroll
        for (int dj = 0; dj < 2; ++dj)
#pragma unroll
            for (int tt = 0; tt < 2; ++tt)
                va[dj][tt] = *(const bf16x8*)&Vlds[cur][dj * 2 + tt][lane * 8];

        // QK^T (swapped): s[mj][nj] = S^T[key kstart+m0+16mj+4hi+r][query nbase+16nj+ll]
        f32x4 s[4][2];
        __builtin_amdgcn_s_setprio(1);
#pragma unroll
        for (int mj = 0; mj < 4; ++mj)
#pragma unroll
            for (int nj = 0; nj < 2; ++nj)
                s[mj][nj] = mfma16(ka[mj], qf[nj], zero);
        __builtin_amdgcn_s_setprio(0);

        // p = exp2(s); lane-local lsum; pack to LDS (stride 34: conflict-free)
#pragma unroll
        for (int mj = 0; mj < 4; ++mj)
#pragma unroll
            for (int nj = 0; nj < 2; ++nj) {
                float p0 = __builtin_amdgcn_exp2f(s[mj][nj][0]);
                float p1 = __builtin_amdgcn_exp2f(s[mj][nj][1]);
                float p2 = __builtin_amdgcn_exp2f(s[mj][nj][2]);
                float p3 = __builtin_amdgcn_exp2f(s[mj][nj][3]);
                lsum[nj] += (p0 + p1) + (p2 + p3);
                *(uint2*)&Plds[wv][16 * nj + ll][8 * mj + 2 * hi] =
                    make_uint2(cvt_pk(p0, p1), cvt_pk(p2, p3));
            }

        // read P as B-fragments
        bf16x8 pbf[2][2];
#pragma unroll
        for (int nj = 0; nj < 2; ++nj)
#pragma unroll
            for (int tt = 0; tt < 2; ++tt) {
                uint2 lo  = *(uint2*)&Plds[wv][16 * nj + ll][16 * tt + 4 * hi];
                uint2 hi2 = *(uint2*)&Plds[wv][16 * nj + ll][16 * tt + 4 * hi + 2];
                pbf[nj][tt] = bc8(lo.x, lo.y, hi2.x, hi2.y);
            }

        __builtin_amdgcn_s_setprio(1);
#pragma unroll
        for (int tt = 0; tt < 2; ++tt)
#pragma unroll
            for (int nj = 0; nj < 2; ++nj)
#pragma unroll
                for (int dj = 0; dj < 2; ++dj)
                    acc[nj][dj] = mfma16(va[dj][tt], pbf[nj][tt], acc[nj][dj]);
        __builtin_amdgcn_s_setprio(0);

        __syncthreads();  // publishes buf^1 (stage drained) + protects buf reuse
        cur ^= 1;
    }

    // partial epilogue (r12-validated): fp32 acc + per-query lsum to workspace
    int qt = qg * 4 + wv;                 // 32-q tile index 0..63
    int w = (bh * 64 + qt) * 2 + kh;
    float* pa = pacc + (size_t)w * 1024;  // [32 q][32 d]
#pragma unroll
    for (int nj = 0; nj < 2; ++nj) {
#pragma unroll
        for (int dj = 0; dj < 2; ++dj)
            *(f32x4*)(pa + (16 * nj + ll) * 32 + 16 * dj + 4 * hi) = acc[nj][dj];
        lsum[nj] += __shfl_xor(lsum[nj], 16);
        lsum[nj] += __shfl_xor(lsum[nj], 32);
        if (hi == 0) plsum[w * 32 + 16 * nj + ll] = lsum[nj];
    }
}

// ---------------------------------------------------------------------------
// Combine split-K halves: out = (accA+accB)/(lA+lB), write h2T bf16 [B][L][C].
// One thread per query (65536 threads). (r12-validated kernel, verbatim.)
// ---------------------------------------------------------------------------
__global__ __launch_bounds__(256) void attn_combine(const float* __restrict__ pacc,
                                                    const float* __restrict__ plsum,
                                                    unsigned short* __restrict__ h2T) {
    int idx = blockIdx.x * 256 + threadIdx.x;   // 0..65535
    int bh = idx >> 11, rem = idx & 2047;       // rem = n
    int b = bh >> 3, h = bh & 7;
    int qt = rem >> 5, q = rem & 31;
    int w0 = (bh * 64 + qt) * 2;
    const float* a0 = pacc + (size_t)w0 * 1024 + q * 32;
    const float* a1 = a0 + 1024;
    float inv = 1.f / (plsum[w0 * 32 + q] + plsum[w0 * 32 + 32 + q]);
    unsigned short* ob = h2T + ((size_t)b * kL + rem) * kC + h * 32;
#pragma unroll
    for (int dd = 0; dd < 4; ++dd) {
        float4 x0 = *(const float4*)(a0 + dd * 8);
        float4 x1 = *(const float4*)(a1 + dd * 8);
        float4 y0 = *(const float4*)(a0 + dd * 8 + 4);
        float4 y1 = *(const float4*)(a1 + dd * 8 + 4);
        *(uint4*)(ob + dd * 8) = make_uint4(
            cvt_pk((x0.x + x1.x) * inv, (x0.y + x1.y) * inv),
            cvt_pk((x0.z + x1.z) * inv, (x0.w + x1.w) * inv),
            cvt_pk((y0.x + y1.x) * inv, (y0.y + y1.y) * inv),
            cvt_pk((y0.z + y1.z) * inv, (y0.w + y1.w) * inv));
    }
}

// ---------------------------------------------------------------------------
// OUT GEMM, W-in-registers. Block: o-tile 64 (wave=16), n-tile 64.
// out[o][n] = sum_c Wout[o][c] h2T[n][c] + bias + x, fp32 out.
// ---------------------------------------------------------------------------
__global__ __launch_bounds__(256) void out_gemm(const unsigned short* __restrict__ Wb,
                                                const unsigned short* __restrict__ h2T,
                                                const float* __restrict__ outb,
                                                const float* __restrict__ x,
                                                float* __restrict__ out) {
    int t = threadIdx.x, wv = t >> 6, ll = t & 15, lg = (t >> 4) & 3;
    int n0 = blockIdx.x * 64, o0 = blockIdx.y * 64, b = blockIdx.z;
    int obase = o0 + wv * 16;
    const unsigned short* hb = h2T + (size_t)b * kL * kC;

    bf16x8 wf[8];
#pragma unroll
    for (int k = 0; k < 8; ++k)
        wf[k] = *(const bf16x8*)(Wb + (size_t)(obase + ll) * 256 + 32 * k + 8 * lg);
    float bias[4];
#pragma unroll
    for (int r = 0; r < 4; ++r) bias[r] = outb[obase + 4 * lg + r];

    for (int np = 0; np < 2; ++np) {
        f32x4 acc0 = {}, acc1 = {};
        int nA = n0 + np * 32 + ll, nB = nA + 16;
#pragma unroll
        for (int k = 0; k < 8; ++k) {
            bf16x8 h0 = *(const bf16x8*)(hb + (size_t)nA * 256 + 32 * k + 8 * lg);
            bf16x8 h1 = *(const bf16x8*)(hb + (size_t)nB * 256 + 32 * k + 8 * lg);
            acc0 = mfma16(wf[k], h0, acc0);
            acc1 = mfma16(wf[k], h1, acc1);
        }
#pragma unroll
        for (int r = 0; r < 4; ++r) {
            size_t row = (size_t)b * kC + obase + 4 * lg + r;
            out[row * kL + nA] = acc0[r] + bias[r] + x[row * kL + nA];
            out[row * kL + nB] = acc1[r] + bias[r] + x[row * kL + nB];
        }
    }
}

// ---------------------------------------------------------------------------
extern "C" void kernel_launch(void* const* d_in, const int* in_sizes, int n_in,
                              void* d_out, int out_size, void* d_ws, size_t ws_size,
                              hipStream_t stream) {
    const float* x     = (const float*)d_in[0];
    const float* gn_w  = (const float*)d_in[1];
    const float* gn_b  = (const float*)d_in[2];
    const float* qkv_w = (const float*)d_in[3];
    const float* qkv_b = (const float*)d_in[4];
    const float* out_w = (const float*)d_in[5];
    const float* out_b = (const float*)d_in[6];
    float* out = (float*)d_out;

    char* ws = (char*)d_ws;
    const size_t MB = 1024 * 1024;
    unsigned short* hT   = (unsigned short*)(ws);             // 0-4 MB
    unsigned short* qT   = (unsigned short*)(ws + 4  * MB);   // 4-8 MB
    unsigned short* kT   = (unsigned short*)(ws + 8  * MB);   // 8-12 MB
    unsigned short* vbuf = (unsigned short*)(ws + 12 * MB);   // 12-16 MB
    unsigned short* h2T  = (unsigned short*)(ws + 16 * MB);   // 16-20 MB
    unsigned short* wqkv = (unsigned short*)(ws + 20 * MB);   // 20-20.375 MB
    unsigned short* wout = (unsigned short*)(ws + 20 * MB + 512 * 1024);
    float* pacc  = (float*)(ws + 21 * MB);                    // 21-37 MB
    float* plsum = (float*)(ws + 37 * MB);                    // 37-37.5 MB

    gncvt_kernel<<<dim3(384), 256, 0, stream>>>(x, gn_w, gn_b, hT, qkv_w, out_w, wqkv, wout);
    qkv_gemm<<<dim3(16, 12, kB), 256, 0, stream>>>(wqkv, hT, qkv_b, qT, kT, vbuf);
    attn_kernel<<<dim3(1024), 256, 0, stream>>>(qT, kT, vbuf, pacc, plsum);
    attn_combine<<<dim3(256), 256, 0, stream>>>(pacc, plsum, h2T);
    out_gemm<<<dim3(32, 4, kB), 256, 0, stream>>>(wout, h2T, out_b, x, out);
}

// Round 17
// 90.810 us; speedup vs baseline: 1.0818x; 1.0818x over previous
//
#include <hip/hip_runtime.h>
#include <math.h>

using f32x4  = __attribute__((ext_vector_type(4))) float;
using bf16x8 = __attribute__((ext_vector_type(8))) short;

constexpr int kB = 4, kC = 256, kL = 2048, kH = 8;
constexpr float kQScale = 0.25505402264f;  // 1/sqrt(32) * log2(e)

__device__ __forceinline__ unsigned short f2bf(float f) {
    unsigned u = __builtin_bit_cast(unsigned, f);
    u += 0x7fffu + ((u >> 16) & 1u);
    return (unsigned short)(u >> 16);
}
__device__ __forceinline__ unsigned cvt_pk(float lo, float hi) {
    unsigned r;
    asm("v_cvt_pk_bf16_f32 %0, %1, %2" : "=v"(r) : "v"(lo), "v"(hi));
    return r;
}
__device__ __forceinline__ f32x4 mfma16(bf16x8 a, bf16x8 b, f32x4 c) {
    return __builtin_amdgcn_mfma_f32_16x16x32_bf16(a, b, c, 0, 0, 0);
}
__device__ __forceinline__ bf16x8 bc8(unsigned a, unsigned b, unsigned c, unsigned d) {
    return __builtin_bit_cast(bf16x8, make_uint4(a, b, c, d));
}
// async global->LDS, 16B per lane; LDS dest = base + lane*16 (HW-linear).
__device__ __forceinline__ void glds16(const unsigned short* g, unsigned short* l) {
    __builtin_amdgcn_global_load_lds(
        (const __attribute__((address_space(1))) unsigned int*)g,
        (__attribute__((address_space(3))) unsigned int*)l, 16, 0, 0);
}

// ---------------------------------------------------------------------------
// Fused GN (blocks 0..127) + weight cvt (blocks 128..383): one launch stage.
// ---------------------------------------------------------------------------
__global__ __launch_bounds__(256) void gncvt_kernel(const float* __restrict__ x,
                                                    const float* __restrict__ gw,
                                                    const float* __restrict__ gb,
                                                    unsigned short* __restrict__ hT,
                                                    const float* __restrict__ qkvw,
                                                    const float* __restrict__ outw,
                                                    unsigned short* __restrict__ wq,
                                                    unsigned short* __restrict__ wo) {
    if (blockIdx.x >= 128) {  // ---- cvt role ----
        int i = (blockIdx.x - 128) * 256 + threadIdx.x;  // 0..65535 float4s
        const float* s; unsigned short* d; int j;
        if (i < 49152) { s = qkvw; d = wq; j = i; }
        else           { s = outw; d = wo; j = i - 49152; }
        float4 v = ((const float4*)s)[j];
        ((uint2*)d)[j] = make_uint2(cvt_pk(v.x, v.y), cvt_pk(v.z, v.w));
        return;
    }
    // ---- groupnorm role ----
    int b = blockIdx.x >> 5, g = blockIdx.x & 31;
    int t = threadIdx.x;
    const float* xp = x + ((size_t)b * kC + g * 8) * kL + 8 * t;

    float v[8][8];
    float s = 0.f, ss = 0.f;
#pragma unroll
    for (int c = 0; c < 8; ++c) {
        float4 a  = *(const float4*)(xp + (size_t)c * kL);
        float4 a2 = *(const float4*)(xp + (size_t)c * kL + 4);
        v[c][0]=a.x; v[c][1]=a.y; v[c][2]=a.z; v[c][3]=a.w;
        v[c][4]=a2.x; v[c][5]=a2.y; v[c][6]=a2.z; v[c][7]=a2.w;
        s  += (a.x+a.y)+(a.z+a.w)+(a2.x+a2.y)+(a2.z+a2.w);
        ss += a.x*a.x+a.y*a.y+a.z*a.z+a.w*a.w+a2.x*a2.x+a2.y*a2.y+a2.z*a2.z+a2.w*a2.w;
    }
#pragma unroll
    for (int off = 32; off; off >>= 1) {
        s  += __shfl_down(s, off);
        ss += __shfl_down(ss, off);
    }
    __shared__ float red[8];
    int wv = t >> 6;
    if ((t & 63) == 0) { red[wv] = s; red[4 + wv] = ss; }
    __syncthreads();
    s  = red[0] + red[1] + red[2] + red[3];
    ss = red[4] + red[5] + red[6] + red[7];
    float mean = s * (1.f / 16384.f);
    float var  = ss * (1.f / 16384.f) - mean * mean;
    float rstd = rsqrtf(var + 1e-5f);

    float wc[8], bc[8];
#pragma unroll
    for (int c = 0; c < 8; ++c) { wc[c] = gw[g*8+c] * rstd; bc[c] = gb[g*8+c]; }

    unsigned short* hp = hT + ((size_t)b * kL + 8 * t) * kC + g * 8;
#pragma unroll
    for (int j = 0; j < 8; ++j) {
        unsigned pk[4];
#pragma unroll
        for (int c2 = 0; c2 < 4; ++c2) {
            pk[c2] = cvt_pk((v[2*c2  ][j] - mean) * wc[2*c2  ] + bc[2*c2  ],
                            (v[2*c2+1][j] - mean) * wc[2*c2+1] + bc[2*c2+1]);
        }
        *(uint4*)(hp + (size_t)j * kC) = make_uint4(pk[0], pk[1], pk[2], pk[3]);
    }
}

// ---------------------------------------------------------------------------
// Merged QKV GEMM, W-in-registers. Block: o-tile 64 (wave=16 rows), n-tile 128.
// q,k stored transposed [B][H][L][32]; v stored [B][256][L].
// q pre-scaled by 1/sqrt(D)*log2(e), bias fused.
// ---------------------------------------------------------------------------
__device__ __forceinline__ void store_qk(unsigned short* __restrict__ base, size_t bh,
                                         int n, int d0, f32x4 acc,
                                         const float* bias4, float scale) {
    float v0 = (acc[0] + bias4[0]) * scale, v1 = (acc[1] + bias4[1]) * scale;
    float v2 = (acc[2] + bias4[2]) * scale, v3 = (acc[3] + bias4[3]) * scale;
    *(uint2*)(base + (bh * kL + n) * 32 + d0) = make_uint2(cvt_pk(v0, v1), cvt_pk(v2, v3));
}

__global__ __launch_bounds__(256) void qkv_gemm(const unsigned short* __restrict__ Wb,
                                                const unsigned short* __restrict__ hT,
                                                const float* __restrict__ qkvb,
                                                unsigned short* __restrict__ qT,
                                                unsigned short* __restrict__ kT,
                                                unsigned short* __restrict__ vbuf) {
    int t = threadIdx.x, wv = t >> 6, ll = t & 15, lg = (t >> 4) & 3;
    int n0 = blockIdx.x * 128, o0 = blockIdx.y * 64, b = blockIdx.z;
    int obase = o0 + wv * 16;
    const unsigned short* hb = hT + (size_t)b * kL * kC;

    bf16x8 wf[8];
#pragma unroll
    for (int k = 0; k < 8; ++k)
        wf[k] = *(const bf16x8*)(Wb + (size_t)(obase + ll) * 256 + 32 * k + 8 * lg);
    float bias[4];
#pragma unroll
    for (int r = 0; r < 4; ++r) bias[r] = qkvb[obase + 4 * lg + r];
    int mode = (obase < 256) ? 0 : (obase < 512 ? 1 : 2);
    int d0 = (obase & 31) + 4 * lg;

    for (int np = 0; np < 4; ++np) {
        f32x4 acc0 = {}, acc1 = {};
        int nA = n0 + np * 32 + ll, nB = nA + 16;
#pragma unroll
        for (int k = 0; k < 8; ++k) {
            bf16x8 h0 = *(const bf16x8*)(hb + (size_t)nA * 256 + 32 * k + 8 * lg);
            bf16x8 h1 = *(const bf16x8*)(hb + (size_t)nB * 256 + 32 * k + 8 * lg);
            acc0 = mfma16(wf[k], h0, acc0);
            acc1 = mfma16(wf[k], h1, acc1);
        }
        if (mode == 0) {
            size_t bh = (size_t)b * kH + (obase >> 5);
            store_qk(qT, bh, nA, d0, acc0, bias, kQScale);
            store_qk(qT, bh, nB, d0, acc1, bias, kQScale);
        } else if (mode == 1) {
            size_t bh = (size_t)b * kH + ((obase - 256) >> 5);
            store_qk(kT, bh, nA, d0, acc0, bias, 1.f);
            store_qk(kT, bh, nB, d0, acc1, bias, 1.f);
        } else {
#pragma unroll
            for (int r = 0; r < 4; ++r) {
                size_t row = (size_t)b * kC + (obase - 512) + 4 * lg + r;
                vbuf[row * kL + nA] = f2bf(acc0[r] + bias[r]);
                vbuf[row * kL + nB] = f2bf(acc1[r] + bias[r]);
            }
        }
    }
}

// ---------------------------------------------------------------------------
// Flash attention v17 = r14 pipeline + T4 counted-vmcnt barriers.
// r16 proved the cost is the __syncthreads vmcnt(0) drain (duration invariant
// to 2x wave supply). Replace with raw s_barrier + explicit waits:
//  - depth-2 prefetch: prologue stages tiles 0,1; iter t stages tile t+2 into
//    the buffer just read. Each wave issues 2 glds/tile.
//  - read-barrier: lgkmcnt(0) (fragments in regs) -> s_barrier -> safe to
//    overwrite buf[cur].
//  - publish-barrier: vmcnt(2) (tile t+1's pair retired, tile t+2's pair
//    STAYS IN FLIGHT across the barrier) -> s_barrier.
// Stage latency now spans ~2 compute phases instead of racing one drain.
// Wave math / Plds stride-34 transpose / lsum order: r14 VERBATIM.
// Block = 4 waves x 32q, one bh; grid 512, XCD-swizzled.
// ---------------------------------------------------------------------------
__global__ __launch_bounds__(256) void attn_kernel(const unsigned short* __restrict__ qT,
                                                   const unsigned short* __restrict__ kT,
                                                   const unsigned short* __restrict__ vbuf,
                                                   unsigned short* __restrict__ h2T) {
    __shared__ alignas(16) unsigned short Klds[2][4][512];  // [buf][mj][frag order]
    __shared__ alignas(16) unsigned short Vlds[2][4][512];  // [buf][dj*2+tt][frag]
    __shared__ unsigned Plds[4][32][34];
    int t = threadIdx.x, wv = t >> 6, ll = t & 15, hi = (t >> 4) & 3;
    int lane = t & 63;
    int j = blockIdx.x;
    int bid = (j & 7) * 64 + (j >> 3);    // XCD swizzle: 512 = 8 x 64, bijective
    int qg = bid & 15, bh = bid >> 4;     // qg 0..15 (128-q groups), bh 0..31
    int b = bh >> 3, h = bh & 7;
    const unsigned short* qb = qT + (size_t)bh * kL * 32;
    const unsigned short* kb = kT + (size_t)bh * kL * 32;
    const unsigned short* vb = vbuf + ((size_t)b * kC + h * 32) * kL;
    int nbase = qg * 128 + wv * 32;       // this wave's 32 queries

    bf16x8 qf[2];
#pragma unroll
    for (int nj = 0; nj < 2; ++nj)
        qf[nj] = *(const bf16x8*)(qb + (size_t)(nbase + 16 * nj + ll) * 32 + 8 * hi);

    f32x4 acc[2][2] = {};                 // [nj][dj]
    float lsum[2] = {0.f, 0.f};
    const f32x4 zero = {0.f, 0.f, 0.f, 0.f};

    // per-lane global source offsets (r14 assignments):
    const unsigned short* ksrc = kb + (size_t)(16 * wv + ll) * 32 + 8 * hi;
    const unsigned short* vsrc = vb + (size_t)(16 * (wv >> 1) + ll) * kL + 32 * (wv & 1) + 8 * hi;

    // prologue: stage tiles 0 and 1 (2 glds each per wave)
    glds16(ksrc, &Klds[0][wv][0]);
    glds16(vsrc, &Vlds[0][wv][0]);
    glds16(ksrc + (size_t)64 * 32, &Klds[1][wv][0]);
    glds16(vsrc + 64,              &Vlds[1][wv][0]);
    asm volatile("s_waitcnt vmcnt(2)" ::: "memory");  // tile 0 landed (own ops)
    __builtin_amdgcn_sched_barrier(0);
    __builtin_amdgcn_s_barrier();                     // tile 0 landed (all waves)

    int cur = 0;
    for (int it = 0; it < 32; ++it) {
        // A: read tile-it fragments from buf[cur] (conflict-free b128)
        bf16x8 ka[4], va[2][2];
#pragma unroll
        for (int mj = 0; mj < 4; ++mj)
            ka[mj] = *(const bf16x8*)&Klds[cur][mj][lane * 8];
#pragma unroll
        for (int dj = 0; dj < 2; ++dj)
#pragma unroll
            for (int tt = 0; tt < 2; ++tt)
                va[dj][tt] = *(const bf16x8*)&Vlds[cur][dj * 2 + tt][lane * 8];

        // B: read-barrier -> buf[cur] may be overwritten
        asm volatile("s_waitcnt lgkmcnt(0)" ::: "memory");
        __builtin_amdgcn_sched_barrier(0);
        __builtin_amdgcn_s_barrier();

        // C: stage tile it+2 into buf[cur] (wraps harmlessly on last 2 iters)
        int kn = ((it + 2) & 31) * 64;
        glds16(ksrc + (size_t)kn * 32, &Klds[cur][wv][0]);
        glds16(vsrc + kn,              &Vlds[cur][wv][0]);

        // D: compute (r14 verbatim)
        f32x4 s[4][2];
        __builtin_amdgcn_s_setprio(1);
#pragma unroll
        for (int mj = 0; mj < 4; ++mj)
#pragma unroll
            for (int nj = 0; nj < 2; ++nj)
                s[mj][nj] = mfma16(ka[mj], qf[nj], zero);
        __builtin_amdgcn_s_setprio(0);

#pragma unroll
        for (int mj = 0; mj < 4; ++mj)
#pragma unroll
            for (int nj = 0; nj < 2; ++nj) {
                float p0 = __builtin_amdgcn_exp2f(s[mj][nj][0]);
                float p1 = __builtin_amdgcn_exp2f(s[mj][nj][1]);
                float p2 = __builtin_amdgcn_exp2f(s[mj][nj][2]);
                float p3 = __builtin_amdgcn_exp2f(s[mj][nj][3]);
                lsum[nj] += (p0 + p1) + (p2 + p3);
                *(uint2*)&Plds[wv][16 * nj + ll][8 * mj + 2 * hi] =
                    make_uint2(cvt_pk(p0, p1), cvt_pk(p2, p3));
            }

        bf16x8 pbf[2][2];
#pragma unroll
        for (int nj = 0; nj < 2; ++nj)
#pragma unroll
            for (int tt = 0; tt < 2; ++tt) {
                uint2 lo  = *(uint2*)&Plds[wv][16 * nj + ll][16 * tt + 4 * hi];
                uint2 hi2 = *(uint2*)&Plds[wv][16 * nj + ll][16 * tt + 4 * hi + 2];
                pbf[nj][tt] = bc8(lo.x, lo.y, hi2.x, hi2.y);
            }

        __builtin_amdgcn_s_setprio(1);
#pragma unroll
        for (int tt = 0; tt < 2; ++tt)
#pragma unroll
            for (int nj = 0; nj < 2; ++nj)
#pragma unroll
                for (int dj = 0; dj < 2; ++dj)
                    acc[nj][dj] = mfma16(va[dj][tt], pbf[nj][tt], acc[nj][dj]);
        __builtin_amdgcn_s_setprio(0);

        // E: publish-barrier with counted vmcnt (tile it+1 retired; it+2 in flight)
        asm volatile("s_waitcnt vmcnt(2)" ::: "memory");
        __builtin_amdgcn_sched_barrier(0);
        __builtin_amdgcn_s_barrier();
        cur ^= 1;
    }
    asm volatile("s_waitcnt vmcnt(0)" ::: "memory");  // retire wrapped dummy stages

#pragma unroll
    for (int nj = 0; nj < 2; ++nj) {
        lsum[nj] += __shfl_xor(lsum[nj], 16);
        lsum[nj] += __shfl_xor(lsum[nj], 32);
        float inv = 1.f / lsum[nj];
        unsigned short* ob = h2T + ((size_t)b * kL + nbase + 16 * nj + ll) * kC + h * 32;
#pragma unroll
        for (int dj = 0; dj < 2; ++dj) {
            *(uint2*)(ob + 16 * dj + 4 * hi) =
                make_uint2(cvt_pk(acc[nj][dj][0] * inv, acc[nj][dj][1] * inv),
                           cvt_pk(acc[nj][dj][2] * inv, acc[nj][dj][3] * inv));
        }
    }
}

// ---------------------------------------------------------------------------
// OUT GEMM, W-in-registers. Block: o-tile 64 (wave=16), n-tile 64.
// out[o][n] = sum_c Wout[o][c] h2T[n][c] + bias + x, fp32 out.
// ---------------------------------------------------------------------------
__global__ __launch_bounds__(256) void out_gemm(const unsigned short* __restrict__ Wb,
                                                const unsigned short* __restrict__ h2T,
                                                const float* __restrict__ outb,
                                                const float* __restrict__ x,
                                                float* __restrict__ out) {
    int t = threadIdx.x, wv = t >> 6, ll = t & 15, lg = (t >> 4) & 3;
    int n0 = blockIdx.x * 64, o0 = blockIdx.y * 64, b = blockIdx.z;
    int obase = o0 + wv * 16;
    const unsigned short* hb = h2T + (size_t)b * kL * kC;

    bf16x8 wf[8];
#pragma unroll
    for (int k = 0; k < 8; ++k)
        wf[k] = *(const bf16x8*)(Wb + (size_t)(obase + ll) * 256 + 32 * k + 8 * lg);
    float bias[4];
#pragma unroll
    for (int r = 0; r < 4; ++r) bias[r] = outb[obase + 4 * lg + r];

    for (int np = 0; np < 2; ++np) {
        f32x4 acc0 = {}, acc1 = {};
        int nA = n0 + np * 32 + ll, nB = nA + 16;
#pragma unroll
        for (int k = 0; k < 8; ++k) {
            bf16x8 h0 = *(const bf16x8*)(hb + (size_t)nA * 256 + 32 * k + 8 * lg);
            bf16x8 h1 = *(const bf16x8*)(hb + (size_t)nB * 256 + 32 * k + 8 * lg);
            acc0 = mfma16(wf[k], h0, acc0);
            acc1 = mfma16(wf[k], h1, acc1);
        }
#pragma unroll
        for (int r = 0; r < 4; ++r) {
            size_t row = (size_t)b * kC + obase + 4 * lg + r;
            out[row * kL + nA] = acc0[r] + bias[r] + x[row * kL + nA];
            out[row * kL + nB] = acc1[r] + bias[r] + x[row * kL + nB];
        }
    }
}

// ---------------------------------------------------------------------------
extern "C" void kernel_launch(void* const* d_in, const int* in_sizes, int n_in,
                              void* d_out, int out_size, void* d_ws, size_t ws_size,
                              hipStream_t stream) {
    const float* x     = (const float*)d_in[0];
    const float* gn_w  = (const float*)d_in[1];
    const float* gn_b  = (const float*)d_in[2];
    const float* qkv_w = (const float*)d_in[3];
    const float* qkv_b = (const float*)d_in[4];
    const float* out_w = (const float*)d_in[5];
    const float* out_b = (const float*)d_in[6];
    float* out = (float*)d_out;

    char* ws = (char*)d_ws;
    const size_t MB = 1024 * 1024;
    unsigned short* hT   = (unsigned short*)(ws);             // 0-4 MB
    unsigned short* qT   = (unsigned short*)(ws + 4  * MB);   // 4-8 MB
    unsigned short* kT   = (unsigned short*)(ws + 8  * MB);   // 8-12 MB
    unsigned short* vbuf = (unsigned short*)(ws + 12 * MB);   // 12-16 MB
    unsigned short* h2T  = (unsigned short*)(ws + 16 * MB);   // 16-20 MB
    unsigned short* wqkv = (unsigned short*)(ws + 20 * MB);   // 20-20.375 MB
    unsigned short* wout = (unsigned short*)(ws + 20 * MB + 512 * 1024);

    gncvt_kernel<<<dim3(384), 256, 0, stream>>>(x, gn_w, gn_b, hT, qkv_w, out_w, wqkv, wout);
    qkv_gemm<<<dim3(16, 12, kB), 256, 0, stream>>>(wqkv, hT, qkv_b, qT, kT, vbuf);
    attn_kernel<<<dim3(512), 256, 0, stream>>>(qT, kT, vbuf, h2T);
    out_gemm<<<dim3(32, 4, kB), 256, 0, stream>>>(wout, h2T, out_b, x, out);
}

// Round 18
// 74.948 us; speedup vs baseline: 1.3107x; 1.2116x over previous
//
#include <hip/hip_runtime.h>
#include <math.h>

using f32x4  = __attribute__((ext_vector_type(4))) float;
using bf16x8 = __attribute__((ext_vector_type(8))) short;

constexpr int kB = 4, kC = 256, kL = 2048, kH = 8;
constexpr float kQScale = 0.25505402264f;  // 1/sqrt(32) * log2(e)

__device__ __forceinline__ unsigned short f2bf(float f) {
    unsigned u = __builtin_bit_cast(unsigned, f);
    u += 0x7fffu + ((u >> 16) & 1u);
    return (unsigned short)(u >> 16);
}
__device__ __forceinline__ unsigned cvt_pk(float lo, float hi) {
    unsigned r;
    asm("v_cvt_pk_bf16_f32 %0, %1, %2" : "=v"(r) : "v"(lo), "v"(hi));
    return r;
}
__device__ __forceinline__ f32x4 mfma16(bf16x8 a, bf16x8 b, f32x4 c) {
    return __builtin_amdgcn_mfma_f32_16x16x32_bf16(a, b, c, 0, 0, 0);
}
__device__ __forceinline__ bf16x8 bc8(unsigned a, unsigned b, unsigned c, unsigned d) {
    return __builtin_bit_cast(bf16x8, make_uint4(a, b, c, d));
}
// async global->LDS, 16B per lane; LDS dest = base + lane*16 (HW-linear).
__device__ __forceinline__ void glds16(const unsigned short* g, unsigned short* l) {
    __builtin_amdgcn_global_load_lds(
        (const __attribute__((address_space(1))) unsigned int*)g,
        (__attribute__((address_space(3))) unsigned int*)l, 16, 0, 0);
}

// ---------------------------------------------------------------------------
// Fused GN (blocks 0..127) + weight cvt (blocks 128..383): one launch stage.
// ---------------------------------------------------------------------------
__global__ __launch_bounds__(256) void gncvt_kernel(const float* __restrict__ x,
                                                    const float* __restrict__ gw,
                                                    const float* __restrict__ gb,
                                                    unsigned short* __restrict__ hT,
                                                    const float* __restrict__ qkvw,
                                                    const float* __restrict__ outw,
                                                    unsigned short* __restrict__ wq,
                                                    unsigned short* __restrict__ wo) {
    if (blockIdx.x >= 128) {  // ---- cvt role ----
        int i = (blockIdx.x - 128) * 256 + threadIdx.x;  // 0..65535 float4s
        const float* s; unsigned short* d; int j;
        if (i < 49152) { s = qkvw; d = wq; j = i; }
        else           { s = outw; d = wo; j = i - 49152; }
        float4 v = ((const float4*)s)[j];
        ((uint2*)d)[j] = make_uint2(cvt_pk(v.x, v.y), cvt_pk(v.z, v.w));
        return;
    }
    // ---- groupnorm role ----
    int b = blockIdx.x >> 5, g = blockIdx.x & 31;
    int t = threadIdx.x;
    const float* xp = x + ((size_t)b * kC + g * 8) * kL + 8 * t;

    float v[8][8];
    float s = 0.f, ss = 0.f;
#pragma unroll
    for (int c = 0; c < 8; ++c) {
        float4 a  = *(const float4*)(xp + (size_t)c * kL);
        float4 a2 = *(const float4*)(xp + (size_t)c * kL + 4);
        v[c][0]=a.x; v[c][1]=a.y; v[c][2]=a.z; v[c][3]=a.w;
        v[c][4]=a2.x; v[c][5]=a2.y; v[c][6]=a2.z; v[c][7]=a2.w;
        s  += (a.x+a.y)+(a.z+a.w)+(a2.x+a2.y)+(a2.z+a2.w);
        ss += a.x*a.x+a.y*a.y+a.z*a.z+a.w*a.w+a2.x*a2.x+a2.y*a2.y+a2.z*a2.z+a2.w*a2.w;
    }
#pragma unroll
    for (int off = 32; off; off >>= 1) {
        s  += __shfl_down(s, off);
        ss += __shfl_down(ss, off);
    }
    __shared__ float red[8];
    int wv = t >> 6;
    if ((t & 63) == 0) { red[wv] = s; red[4 + wv] = ss; }
    __syncthreads();
    s  = red[0] + red[1] + red[2] + red[3];
    ss = red[4] + red[5] + red[6] + red[7];
    float mean = s * (1.f / 16384.f);
    float var  = ss * (1.f / 16384.f) - mean * mean;
    float rstd = rsqrtf(var + 1e-5f);

    float wc[8], bc[8];
#pragma unroll
    for (int c = 0; c < 8; ++c) { wc[c] = gw[g*8+c] * rstd; bc[c] = gb[g*8+c]; }

    unsigned short* hp = hT + ((size_t)b * kL + 8 * t) * kC + g * 8;
#pragma unroll
    for (int j = 0; j < 8; ++j) {
        unsigned pk[4];
#pragma unroll
        for (int c2 = 0; c2 < 4; ++c2) {
            pk[c2] = cvt_pk((v[2*c2  ][j] - mean) * wc[2*c2  ] + bc[2*c2  ],
                            (v[2*c2+1][j] - mean) * wc[2*c2+1] + bc[2*c2+1]);
        }
        *(uint4*)(hp + (size_t)j * kC) = make_uint4(pk[0], pk[1], pk[2], pk[3]);
    }
}

// ---------------------------------------------------------------------------
// Merged QKV GEMM v2: W-in-registers + LDS-staged B shared by all 4 waves.
// r17's pipeline ported: per 32-k chunk, each wave stages its 2 nj sub-tiles
// via glds16 (fragment order), reads 8 conflict-free b128 fragments, runs 8
// independent-chain MFMAs; raw barriers with counted vmcnt(2) keep the next
// chunk's stage in flight across the barrier. k-accumulation order per output
// unchanged (ascending k) -> bit-identical results.
// Block: o-tile 64 (wave=16 rows), n-tile 128 (8 nj). Grid (16,12,4)=768.
// ---------------------------------------------------------------------------
__device__ __forceinline__ void store_qk(unsigned short* __restrict__ base, size_t bh,
                                         int n, int d0, f32x4 acc,
                                         const float* bias4, float scale) {
    float v0 = (acc[0] + bias4[0]) * scale, v1 = (acc[1] + bias4[1]) * scale;
    float v2 = (acc[2] + bias4[2]) * scale, v3 = (acc[3] + bias4[3]) * scale;
    *(uint2*)(base + (bh * kL + n) * 32 + d0) = make_uint2(cvt_pk(v0, v1), cvt_pk(v2, v3));
}

__global__ __launch_bounds__(256) void qkv_gemm(const unsigned short* __restrict__ Wb,
                                                const unsigned short* __restrict__ hT,
                                                const float* __restrict__ qkvb,
                                                unsigned short* __restrict__ qT,
                                                unsigned short* __restrict__ kT,
                                                unsigned short* __restrict__ vbuf) {
    __shared__ alignas(16) unsigned short Hlds[2][8][512];
    int t = threadIdx.x, wv = t >> 6, ll = t & 15, lg = (t >> 4) & 3;
    int lane = t & 63;
    int n0 = blockIdx.x * 128, o0 = blockIdx.y * 64, b = blockIdx.z;
    int obase = o0 + wv * 16;
    const unsigned short* hb = hT + (size_t)b * kL * kC;

    bf16x8 wf[8];
#pragma unroll
    for (int k = 0; k < 8; ++k)
        wf[k] = *(const bf16x8*)(Wb + (size_t)(obase + ll) * 256 + 32 * k + 8 * lg);
    float bias[4];
#pragma unroll
    for (int r = 0; r < 4; ++r) bias[r] = qkvb[obase + 4 * lg + r];
    int mode = (obase < 256) ? 0 : (obase < 512 ? 1 : 2);
    int d0 = (obase & 31) + 4 * lg;

    // staging sources: wave stages sub-tiles nj = 2wv and 2wv+1
    const unsigned short* hsrc0 = hb + (size_t)(n0 + 16 * (2 * wv)     + ll) * 256 + 8 * lg;
    const unsigned short* hsrc1 = hb + (size_t)(n0 + 16 * (2 * wv + 1) + ll) * 256 + 8 * lg;

    glds16(hsrc0,      &Hlds[0][2 * wv][0]);
    glds16(hsrc1,      &Hlds[0][2 * wv + 1][0]);
    glds16(hsrc0 + 32, &Hlds[1][2 * wv][0]);
    glds16(hsrc1 + 32, &Hlds[1][2 * wv + 1][0]);
    asm volatile("s_waitcnt vmcnt(2)" ::: "memory");
    __builtin_amdgcn_sched_barrier(0);
    __builtin_amdgcn_s_barrier();

    f32x4 acc[8] = {};
    int cur = 0;
    for (int c = 0; c < 8; ++c) {
        bf16x8 hf[8];
#pragma unroll
        for (int nj = 0; nj < 8; ++nj)
            hf[nj] = *(const bf16x8*)&Hlds[cur][nj][lane * 8];
        asm volatile("s_waitcnt lgkmcnt(0)" ::: "memory");
        __builtin_amdgcn_sched_barrier(0);
        __builtin_amdgcn_s_barrier();

        int kn = ((c + 2) & 7) * 32;   // wrapped dummy stage on last 2 chunks
        glds16(hsrc0 + kn, &Hlds[cur][2 * wv][0]);
        glds16(hsrc1 + kn, &Hlds[cur][2 * wv + 1][0]);

        __builtin_amdgcn_s_setprio(1);
#pragma unroll
        for (int nj = 0; nj < 8; ++nj)
            acc[nj] = mfma16(wf[c], hf[nj], acc[nj]);
        __builtin_amdgcn_s_setprio(0);

        asm volatile("s_waitcnt vmcnt(2)" ::: "memory");
        __builtin_amdgcn_sched_barrier(0);
        __builtin_amdgcn_s_barrier();
        cur ^= 1;
    }
    asm volatile("s_waitcnt vmcnt(0)" ::: "memory");

#pragma unroll
    for (int nj = 0; nj < 8; ++nj) {
        int n = n0 + 16 * nj + ll;
        if (mode == 0) {
            store_qk(qT, (size_t)b * kH + (obase >> 5), n, d0, acc[nj], bias, kQScale);
        } else if (mode == 1) {
            store_qk(kT, (size_t)b * kH + ((obase - 256) >> 5), n, d0, acc[nj], bias, 1.f);
        } else {
#pragma unroll
            for (int r = 0; r < 4; ++r) {
                size_t row = (size_t)b * kC + (obase - 512) + 4 * lg + r;
                vbuf[row * kL + n] = f2bf(acc[nj][r] + bias[r]);
            }
        }
    }
}

// ---------------------------------------------------------------------------
// Flash attention v17 (unchanged from r17, best attn: 43.9us, absmax 0.03125).
// ---------------------------------------------------------------------------
__global__ __launch_bounds__(256) void attn_kernel(const unsigned short* __restrict__ qT,
                                                   const unsigned short* __restrict__ kT,
                                                   const unsigned short* __restrict__ vbuf,
                                                   unsigned short* __restrict__ h2T) {
    __shared__ alignas(16) unsigned short Klds[2][4][512];
    __shared__ alignas(16) unsigned short Vlds[2][4][512];
    __shared__ unsigned Plds[4][32][34];
    int t = threadIdx.x, wv = t >> 6, ll = t & 15, hi = (t >> 4) & 3;
    int lane = t & 63;
    int j = blockIdx.x;
    int bid = (j & 7) * 64 + (j >> 3);    // XCD swizzle: 512 = 8 x 64, bijective
    int qg = bid & 15, bh = bid >> 4;
    int b = bh >> 3, h = bh & 7;
    const unsigned short* qb = qT + (size_t)bh * kL * 32;
    const unsigned short* kb = kT + (size_t)bh * kL * 32;
    const unsigned short* vb = vbuf + ((size_t)b * kC + h * 32) * kL;
    int nbase = qg * 128 + wv * 32;

    bf16x8 qf[2];
#pragma unroll
    for (int nj = 0; nj < 2; ++nj)
        qf[nj] = *(const bf16x8*)(qb + (size_t)(nbase + 16 * nj + ll) * 32 + 8 * hi);

    f32x4 acc[2][2] = {};
    float lsum[2] = {0.f, 0.f};
    const f32x4 zero = {0.f, 0.f, 0.f, 0.f};

    const unsigned short* ksrc = kb + (size_t)(16 * wv + ll) * 32 + 8 * hi;
    const unsigned short* vsrc = vb + (size_t)(16 * (wv >> 1) + ll) * kL + 32 * (wv & 1) + 8 * hi;

    glds16(ksrc, &Klds[0][wv][0]);
    glds16(vsrc, &Vlds[0][wv][0]);
    glds16(ksrc + (size_t)64 * 32, &Klds[1][wv][0]);
    glds16(vsrc + 64,              &Vlds[1][wv][0]);
    asm volatile("s_waitcnt vmcnt(2)" ::: "memory");
    __builtin_amdgcn_sched_barrier(0);
    __builtin_amdgcn_s_barrier();

    int cur = 0;
    for (int it = 0; it < 32; ++it) {
        bf16x8 ka[4], va[2][2];
#pragma unroll
        for (int mj = 0; mj < 4; ++mj)
            ka[mj] = *(const bf16x8*)&Klds[cur][mj][lane * 8];
#pragma unroll
        for (int dj = 0; dj < 2; ++dj)
#pragma unroll
            for (int tt = 0; tt < 2; ++tt)
                va[dj][tt] = *(const bf16x8*)&Vlds[cur][dj * 2 + tt][lane * 8];

        asm volatile("s_waitcnt lgkmcnt(0)" ::: "memory");
        __builtin_amdgcn_sched_barrier(0);
        __builtin_amdgcn_s_barrier();

        int kn = ((it + 2) & 31) * 64;
        glds16(ksrc + (size_t)kn * 32, &Klds[cur][wv][0]);
        glds16(vsrc + kn,              &Vlds[cur][wv][0]);

        f32x4 s[4][2];
        __builtin_amdgcn_s_setprio(1);
#pragma unroll
        for (int mj = 0; mj < 4; ++mj)
#pragma unroll
            for (int nj = 0; nj < 2; ++nj)
                s[mj][nj] = mfma16(ka[mj], qf[nj], zero);
        __builtin_amdgcn_s_setprio(0);

#pragma unroll
        for (int mj = 0; mj < 4; ++mj)
#pragma unroll
            for (int nj = 0; nj < 2; ++nj) {
                float p0 = __builtin_amdgcn_exp2f(s[mj][nj][0]);
                float p1 = __builtin_amdgcn_exp2f(s[mj][nj][1]);
                float p2 = __builtin_amdgcn_exp2f(s[mj][nj][2]);
                float p3 = __builtin_amdgcn_exp2f(s[mj][nj][3]);
                lsum[nj] += (p0 + p1) + (p2 + p3);
                *(uint2*)&Plds[wv][16 * nj + ll][8 * mj + 2 * hi] =
                    make_uint2(cvt_pk(p0, p1), cvt_pk(p2, p3));
            }

        bf16x8 pbf[2][2];
#pragma unroll
        for (int nj = 0; nj < 2; ++nj)
#pragma unroll
            for (int tt = 0; tt < 2; ++tt) {
                uint2 lo  = *(uint2*)&Plds[wv][16 * nj + ll][16 * tt + 4 * hi];
                uint2 hi2 = *(uint2*)&Plds[wv][16 * nj + ll][16 * tt + 4 * hi + 2];
                pbf[nj][tt] = bc8(lo.x, lo.y, hi2.x, hi2.y);
            }

        __builtin_amdgcn_s_setprio(1);
#pragma unroll
        for (int tt = 0; tt < 2; ++tt)
#pragma unroll
            for (int nj = 0; nj < 2; ++nj)
#pragma unroll
                for (int dj = 0; dj < 2; ++dj)
                    acc[nj][dj] = mfma16(va[dj][tt], pbf[nj][tt], acc[nj][dj]);
        __builtin_amdgcn_s_setprio(0);

        asm volatile("s_waitcnt vmcnt(2)" ::: "memory");
        __builtin_amdgcn_sched_barrier(0);
        __builtin_amdgcn_s_barrier();
        cur ^= 1;
    }
    asm volatile("s_waitcnt vmcnt(0)" ::: "memory");

#pragma unroll
    for (int nj = 0; nj < 2; ++nj) {
        lsum[nj] += __shfl_xor(lsum[nj], 16);
        lsum[nj] += __shfl_xor(lsum[nj], 32);
        float inv = 1.f / lsum[nj];
        unsigned short* ob = h2T + ((size_t)b * kL + nbase + 16 * nj + ll) * kC + h * 32;
#pragma unroll
        for (int dj = 0; dj < 2; ++dj) {
            *(uint2*)(ob + 16 * dj + 4 * hi) =
                make_uint2(cvt_pk(acc[nj][dj][0] * inv, acc[nj][dj][1] * inv),
                           cvt_pk(acc[nj][dj][2] * inv, acc[nj][dj][3] * inv));
        }
    }
}

// ---------------------------------------------------------------------------
// OUT GEMM v2: same staged-B pipeline as qkv_gemm v2 (M=256, bias+residual
// epilogue, fp32 out). Block: o-tile 64, n-tile 128. Grid (16,4,4)=256.
// ---------------------------------------------------------------------------
__global__ __launch_bounds__(256) void out_gemm(const unsigned short* __restrict__ Wb,
                                                const unsigned short* __restrict__ h2T,
                                                const float* __restrict__ outb,
                                                const float* __restrict__ x,
                                                float* __restrict__ out) {
    __shared__ alignas(16) unsigned short Hlds[2][8][512];
    int t = threadIdx.x, wv = t >> 6, ll = t & 15, lg = (t >> 4) & 3;
    int lane = t & 63;
    int n0 = blockIdx.x * 128, o0 = blockIdx.y * 64, b = blockIdx.z;
    int obase = o0 + wv * 16;
    const unsigned short* hb = h2T + (size_t)b * kL * kC;

    bf16x8 wf[8];
#pragma unroll
    for (int k = 0; k < 8; ++k)
        wf[k] = *(const bf16x8*)(Wb + (size_t)(obase + ll) * 256 + 32 * k + 8 * lg);
    float bias[4];
#pragma unroll
    for (int r = 0; r < 4; ++r) bias[r] = outb[obase + 4 * lg + r];

    const unsigned short* hsrc0 = hb + (size_t)(n0 + 16 * (2 * wv)     + ll) * 256 + 8 * lg;
    const unsigned short* hsrc1 = hb + (size_t)(n0 + 16 * (2 * wv + 1) + ll) * 256 + 8 * lg;

    glds16(hsrc0,      &Hlds[0][2 * wv][0]);
    glds16(hsrc1,      &Hlds[0][2 * wv + 1][0]);
    glds16(hsrc0 + 32, &Hlds[1][2 * wv][0]);
    glds16(hsrc1 + 32, &Hlds[1][2 * wv + 1][0]);
    asm volatile("s_waitcnt vmcnt(2)" ::: "memory");
    __builtin_amdgcn_sched_barrier(0);
    __builtin_amdgcn_s_barrier();

    f32x4 acc[8] = {};
    int cur = 0;
    for (int c = 0; c < 8; ++c) {
        bf16x8 hf[8];
#pragma unroll
        for (int nj = 0; nj < 8; ++nj)
            hf[nj] = *(const bf16x8*)&Hlds[cur][nj][lane * 8];
        asm volatile("s_waitcnt lgkmcnt(0)" ::: "memory");
        __builtin_amdgcn_sched_barrier(0);
        __builtin_amdgcn_s_barrier();

        int kn = ((c + 2) & 7) * 32;
        glds16(hsrc0 + kn, &Hlds[cur][2 * wv][0]);
        glds16(hsrc1 + kn, &Hlds[cur][2 * wv + 1][0]);

        __builtin_amdgcn_s_setprio(1);
#pragma unroll
        for (int nj = 0; nj < 8; ++nj)
            acc[nj] = mfma16(wf[c], hf[nj], acc[nj]);
        __builtin_amdgcn_s_setprio(0);

        asm volatile("s_waitcnt vmcnt(2)" ::: "memory");
        __builtin_amdgcn_sched_barrier(0);
        __builtin_amdgcn_s_barrier();
        cur ^= 1;
    }
    asm volatile("s_waitcnt vmcnt(0)" ::: "memory");

#pragma unroll
    for (int nj = 0; nj < 8; ++nj) {
        int n = n0 + 16 * nj + ll;
#pragma unroll
        for (int r = 0; r < 4; ++r) {
            size_t row = (size_t)b * kC + obase + 4 * lg + r;
            out[row * kL + n] = acc[nj][r] + bias[r] + x[row * kL + n];
        }
    }
}

// ---------------------------------------------------------------------------
extern "C" void kernel_launch(void* const* d_in, const int* in_sizes, int n_in,
                              void* d_out, int out_size, void* d_ws, size_t ws_size,
                              hipStream_t stream) {
    const float* x     = (const float*)d_in[0];
    const float* gn_w  = (const float*)d_in[1];
    const float* gn_b  = (const float*)d_in[2];
    const float* qkv_w = (const float*)d_in[3];
    const float* qkv_b = (const float*)d_in[4];
    const float* out_w = (const float*)d_in[5];
    const float* out_b = (const float*)d_in[6];
    float* out = (float*)d_out;

    char* ws = (char*)d_ws;
    const size_t MB = 1024 * 1024;
    unsigned short* hT   = (unsigned short*)(ws);             // 0-4 MB
    unsigned short* qT   = (unsigned short*)(ws + 4  * MB);   // 4-8 MB
    unsigned short* kT   = (unsigned short*)(ws + 8  * MB);   // 8-12 MB
    unsigned short* vbuf = (unsigned short*)(ws + 12 * MB);   // 12-16 MB
    unsigned short* h2T  = (unsigned short*)(ws + 16 * MB);   // 16-20 MB
    unsigned short* wqkv = (unsigned short*)(ws + 20 * MB);   // 20-20.375 MB
    unsigned short* wout = (unsigned short*)(ws + 20 * MB + 512 * 1024);

    gncvt_kernel<<<dim3(384), 256, 0, stream>>>(x, gn_w, gn_b, hT, qkv_w, out_w, wqkv, wout);
    qkv_gemm<<<dim3(16, 12, kB), 256, 0, stream>>>(wqkv, hT, qkv_b, qT, kT, vbuf);
    attn_kernel<<<dim3(512), 256, 0, stream>>>(qT, kT, vbuf, h2T);
    out_gemm<<<dim3(16, 4, kB), 256, 0, stream>>>(wout, h2T, out_b, x, out);
}

// Round 19
// 73.320 us; speedup vs baseline: 1.3398x; 1.0222x over previous
//
#include <hip/hip_runtime.h>
#include <math.h>

using f32x4  = __attribute__((ext_vector_type(4))) float;
using bf16x8 = __attribute__((ext_vector_type(8))) short;

constexpr int kB = 4, kC = 256, kL = 2048, kH = 8;
constexpr float kQScale = 0.25505402264f;  // 1/sqrt(32) * log2(e)

__device__ __forceinline__ unsigned short f2bf(float f) {
    unsigned u = __builtin_bit_cast(unsigned, f);
    u += 0x7fffu + ((u >> 16) & 1u);
    return (unsigned short)(u >> 16);
}
__device__ __forceinline__ unsigned cvt_pk(float lo, float hi) {
    unsigned r;
    asm("v_cvt_pk_bf16_f32 %0, %1, %2" : "=v"(r) : "v"(lo), "v"(hi));
    return r;
}
__device__ __forceinline__ f32x4 mfma16(bf16x8 a, bf16x8 b, f32x4 c) {
    return __builtin_amdgcn_mfma_f32_16x16x32_bf16(a, b, c, 0, 0, 0);
}
__device__ __forceinline__ bf16x8 bc8(unsigned a, unsigned b, unsigned c, unsigned d) {
    return __builtin_bit_cast(bf16x8, make_uint4(a, b, c, d));
}
// async global->LDS, 16B per lane; LDS dest = base + lane*16 (HW-linear).
__device__ __forceinline__ void glds16(const unsigned short* g, unsigned short* l) {
    __builtin_amdgcn_global_load_lds(
        (const __attribute__((address_space(1))) unsigned int*)g,
        (__attribute__((address_space(3))) unsigned int*)l, 16, 0, 0);
}

// ---------------------------------------------------------------------------
// Fused GN (blocks 0..127) + weight cvt (blocks 128..383): one launch stage.
// ---------------------------------------------------------------------------
__global__ __launch_bounds__(256) void gncvt_kernel(const float* __restrict__ x,
                                                    const float* __restrict__ gw,
                                                    const float* __restrict__ gb,
                                                    unsigned short* __restrict__ hT,
                                                    const float* __restrict__ qkvw,
                                                    const float* __restrict__ outw,
                                                    unsigned short* __restrict__ wq,
                                                    unsigned short* __restrict__ wo) {
    if (blockIdx.x >= 128) {  // ---- cvt role ----
        int i = (blockIdx.x - 128) * 256 + threadIdx.x;  // 0..65535 float4s
        const float* s; unsigned short* d; int j;
        if (i < 49152) { s = qkvw; d = wq; j = i; }
        else           { s = outw; d = wo; j = i - 49152; }
        float4 v = ((const float4*)s)[j];
        ((uint2*)d)[j] = make_uint2(cvt_pk(v.x, v.y), cvt_pk(v.z, v.w));
        return;
    }
    // ---- groupnorm role ----
    int b = blockIdx.x >> 5, g = blockIdx.x & 31;
    int t = threadIdx.x;
    const float* xp = x + ((size_t)b * kC + g * 8) * kL + 8 * t;

    float v[8][8];
    float s = 0.f, ss = 0.f;
#pragma unroll
    for (int c = 0; c < 8; ++c) {
        float4 a  = *(const float4*)(xp + (size_t)c * kL);
        float4 a2 = *(const float4*)(xp + (size_t)c * kL + 4);
        v[c][0]=a.x; v[c][1]=a.y; v[c][2]=a.z; v[c][3]=a.w;
        v[c][4]=a2.x; v[c][5]=a2.y; v[c][6]=a2.z; v[c][7]=a2.w;
        s  += (a.x+a.y)+(a.z+a.w)+(a2.x+a2.y)+(a2.z+a2.w);
        ss += a.x*a.x+a.y*a.y+a.z*a.z+a.w*a.w+a2.x*a2.x+a2.y*a2.y+a2.z*a2.z+a2.w*a2.w;
    }
#pragma unroll
    for (int off = 32; off; off >>= 1) {
        s  += __shfl_down(s, off);
        ss += __shfl_down(ss, off);
    }
    __shared__ float red[8];
    int wv = t >> 6;
    if ((t & 63) == 0) { red[wv] = s; red[4 + wv] = ss; }
    __syncthreads();
    s  = red[0] + red[1] + red[2] + red[3];
    ss = red[4] + red[5] + red[6] + red[7];
    float mean = s * (1.f / 16384.f);
    float var  = ss * (1.f / 16384.f) - mean * mean;
    float rstd = rsqrtf(var + 1e-5f);

    float wc[8], bc[8];
#pragma unroll
    for (int c = 0; c < 8; ++c) { wc[c] = gw[g*8+c] * rstd; bc[c] = gb[g*8+c]; }

    unsigned short* hp = hT + ((size_t)b * kL + 8 * t) * kC + g * 8;
#pragma unroll
    for (int j = 0; j < 8; ++j) {
        unsigned pk[4];
#pragma unroll
        for (int c2 = 0; c2 < 4; ++c2) {
            pk[c2] = cvt_pk((v[2*c2  ][j] - mean) * wc[2*c2  ] + bc[2*c2  ],
                            (v[2*c2+1][j] - mean) * wc[2*c2+1] + bc[2*c2+1]);
        }
        *(uint4*)(hp + (size_t)j * kC) = make_uint4(pk[0], pk[1], pk[2], pk[3]);
    }
}

// ---------------------------------------------------------------------------
// Merged QKV GEMM v2 (r18, unchanged): W-in-registers + LDS-staged B shared by
// all 4 waves, counted-vmcnt barriers.
// ---------------------------------------------------------------------------
__device__ __forceinline__ void store_qk(unsigned short* __restrict__ base, size_t bh,
                                         int n, int d0, f32x4 acc,
                                         const float* bias4, float scale) {
    float v0 = (acc[0] + bias4[0]) * scale, v1 = (acc[1] + bias4[1]) * scale;
    float v2 = (acc[2] + bias4[2]) * scale, v3 = (acc[3] + bias4[3]) * scale;
    *(uint2*)(base + (bh * kL + n) * 32 + d0) = make_uint2(cvt_pk(v0, v1), cvt_pk(v2, v3));
}

__global__ __launch_bounds__(256) void qkv_gemm(const unsigned short* __restrict__ Wb,
                                                const unsigned short* __restrict__ hT,
                                                const float* __restrict__ qkvb,
                                                unsigned short* __restrict__ qT,
                                                unsigned short* __restrict__ kT,
                                                unsigned short* __restrict__ vbuf) {
    __shared__ alignas(16) unsigned short Hlds[2][8][512];
    int t = threadIdx.x, wv = t >> 6, ll = t & 15, lg = (t >> 4) & 3;
    int lane = t & 63;
    int n0 = blockIdx.x * 128, o0 = blockIdx.y * 64, b = blockIdx.z;
    int obase = o0 + wv * 16;
    const unsigned short* hb = hT + (size_t)b * kL * kC;

    bf16x8 wf[8];
#pragma unroll
    for (int k = 0; k < 8; ++k)
        wf[k] = *(const bf16x8*)(Wb + (size_t)(obase + ll) * 256 + 32 * k + 8 * lg);
    float bias[4];
#pragma unroll
    for (int r = 0; r < 4; ++r) bias[r] = qkvb[obase + 4 * lg + r];
    int mode = (obase < 256) ? 0 : (obase < 512 ? 1 : 2);
    int d0 = (obase & 31) + 4 * lg;

    const unsigned short* hsrc0 = hb + (size_t)(n0 + 16 * (2 * wv)     + ll) * 256 + 8 * lg;
    const unsigned short* hsrc1 = hb + (size_t)(n0 + 16 * (2 * wv + 1) + ll) * 256 + 8 * lg;

    glds16(hsrc0,      &Hlds[0][2 * wv][0]);
    glds16(hsrc1,      &Hlds[0][2 * wv + 1][0]);
    glds16(hsrc0 + 32, &Hlds[1][2 * wv][0]);
    glds16(hsrc1 + 32, &Hlds[1][2 * wv + 1][0]);
    asm volatile("s_waitcnt vmcnt(2)" ::: "memory");
    __builtin_amdgcn_sched_barrier(0);
    __builtin_amdgcn_s_barrier();

    f32x4 acc[8] = {};
    int cur = 0;
    for (int c = 0; c < 8; ++c) {
        bf16x8 hf[8];
#pragma unroll
        for (int nj = 0; nj < 8; ++nj)
            hf[nj] = *(const bf16x8*)&Hlds[cur][nj][lane * 8];
        asm volatile("s_waitcnt lgkmcnt(0)" ::: "memory");
        __builtin_amdgcn_sched_barrier(0);
        __builtin_amdgcn_s_barrier();

        int kn = ((c + 2) & 7) * 32;
        glds16(hsrc0 + kn, &Hlds[cur][2 * wv][0]);
        glds16(hsrc1 + kn, &Hlds[cur][2 * wv + 1][0]);

        __builtin_amdgcn_s_setprio(1);
#pragma unroll
        for (int nj = 0; nj < 8; ++nj)
            acc[nj] = mfma16(wf[c], hf[nj], acc[nj]);
        __builtin_amdgcn_s_setprio(0);

        asm volatile("s_waitcnt vmcnt(2)" ::: "memory");
        __builtin_amdgcn_sched_barrier(0);
        __builtin_amdgcn_s_barrier();
        cur ^= 1;
    }
    asm volatile("s_waitcnt vmcnt(0)" ::: "memory");

#pragma unroll
    for (int nj = 0; nj < 8; ++nj) {
        int n = n0 + 16 * nj + ll;
        if (mode == 0) {
            store_qk(qT, (size_t)b * kH + (obase >> 5), n, d0, acc[nj], bias, kQScale);
        } else if (mode == 1) {
            store_qk(kT, (size_t)b * kH + ((obase - 256) >> 5), n, d0, acc[nj], bias, 1.f);
        } else {
#pragma unroll
            for (int r = 0; r < 4; ++r) {
                size_t row = (size_t)b * kC + (obase - 512) + 4 * lg + r;
                vbuf[row * kL + n] = f2bf(acc[nj][r] + bias[r]);
            }
        }
    }
}

// ---------------------------------------------------------------------------
// Flash attention v19 = r17 counted-vmcnt pipeline + r15's 128-key tiles:
// 16 iters (half the barriers / Plds round-trips), grid stays 512 = 2/CU,
// tail-free (r15's regression was the 3/CU tail, not the tile size).
// Per-query key order, lsum add order, PV accumulation order = r17's exact
// sequence (two consecutive 64-tiles concatenated) -> absmax 0.03125.
// LDS: K 16KB + V 16KB + Plds[4][32][66] 33.8KB = 65.8KB -> 2 blocks/CU.
// Each wave stages 4 sub-tiles/tile (2 K + 2 V) -> counted vmcnt(4).
// ---------------------------------------------------------------------------
__global__ __launch_bounds__(256) void attn_kernel(const unsigned short* __restrict__ qT,
                                                   const unsigned short* __restrict__ kT,
                                                   const unsigned short* __restrict__ vbuf,
                                                   unsigned short* __restrict__ h2T) {
    __shared__ alignas(16) unsigned short Klds[2][8][512];  // [buf][mj][frag order]
    __shared__ alignas(16) unsigned short Vlds[2][8][512];  // [buf][dj*4+tt][frag]
    __shared__ unsigned Plds[4][32][66];
    int t = threadIdx.x, wv = t >> 6, ll = t & 15, hi = (t >> 4) & 3;
    int lane = t & 63;
    int j = blockIdx.x;
    int bid = (j & 7) * 64 + (j >> 3);    // XCD swizzle: 512 = 8 x 64, bijective
    int qg = bid & 15, bh = bid >> 4;     // qg 0..15 (128-q groups), bh 0..31
    int b = bh >> 3, h = bh & 7;
    const unsigned short* qb = qT + (size_t)bh * kL * 32;
    const unsigned short* kb = kT + (size_t)bh * kL * 32;
    const unsigned short* vb = vbuf + ((size_t)b * kC + h * 32) * kL;
    int nbase = qg * 128 + wv * 32;       // this wave's 32 queries

    bf16x8 qf[2];
#pragma unroll
    for (int nj = 0; nj < 2; ++nj)
        qf[nj] = *(const bf16x8*)(qb + (size_t)(nbase + 16 * nj + ll) * 32 + 8 * hi);

    f32x4 acc[2][2] = {};                 // [nj][dj]
    float lsum[2] = {0.f, 0.f};
    const f32x4 zero = {0.f, 0.f, 0.f, 0.f};

    // staging: wave stages K sub-tiles {wv, wv+4}, V sub-tiles {(0,wv),(1,wv)}
    const unsigned short* ksrc0 = kb + (size_t)(16 * wv + ll) * 32 + 8 * hi;
    const unsigned short* ksrc1 = kb + (size_t)(16 * (wv + 4) + ll) * 32 + 8 * hi;
    const unsigned short* vsrc0 = vb + (size_t)ll * kL + 32 * wv + 8 * hi;
    const unsigned short* vsrc1 = vb + (size_t)(16 + ll) * kL + 32 * wv + 8 * hi;

    // prologue: stage tiles 0 and 1 (4 glds each per wave)
    glds16(ksrc0, &Klds[0][wv][0]);
    glds16(ksrc1, &Klds[0][wv + 4][0]);
    glds16(vsrc0, &Vlds[0][wv][0]);
    glds16(vsrc1, &Vlds[0][wv + 4][0]);
    glds16(ksrc0 + (size_t)128 * 32, &Klds[1][wv][0]);
    glds16(ksrc1 + (size_t)128 * 32, &Klds[1][wv + 4][0]);
    glds16(vsrc0 + 128, &Vlds[1][wv][0]);
    glds16(vsrc1 + 128, &Vlds[1][wv + 4][0]);
    asm volatile("s_waitcnt vmcnt(4)" ::: "memory");  // tile 0 landed (own ops)
    __builtin_amdgcn_sched_barrier(0);
    __builtin_amdgcn_s_barrier();

    int cur = 0;
    for (int it = 0; it < 16; ++it) {
        // A: read tile-it fragments (conflict-free b128)
        bf16x8 ka[8], va[2][4];
#pragma unroll
        for (int mj = 0; mj < 8; ++mj)
            ka[mj] = *(const bf16x8*)&Klds[cur][mj][lane * 8];
#pragma unroll
        for (int dj = 0; dj < 2; ++dj)
#pragma unroll
            for (int tt = 0; tt < 4; ++tt)
                va[dj][tt] = *(const bf16x8*)&Vlds[cur][dj * 4 + tt][lane * 8];

        // B: read-barrier -> buf[cur] may be overwritten
        asm volatile("s_waitcnt lgkmcnt(0)" ::: "memory");
        __builtin_amdgcn_sched_barrier(0);
        __builtin_amdgcn_s_barrier();

        // C: stage tile it+2 into buf[cur] (wraps harmlessly on last 2 iters)
        int kn = ((it + 2) & 15) * 128;
        glds16(ksrc0 + (size_t)kn * 32, &Klds[cur][wv][0]);
        glds16(ksrc1 + (size_t)kn * 32, &Klds[cur][wv + 4][0]);
        glds16(vsrc0 + kn, &Vlds[cur][wv][0]);
        glds16(vsrc1 + kn, &Vlds[cur][wv + 4][0]);

        // D: compute — QK^T: s[mj][nj] over 128 keys (ascending key order)
        f32x4 s[8][2];
        __builtin_amdgcn_s_setprio(1);
#pragma unroll
        for (int mj = 0; mj < 8; ++mj)
#pragma unroll
            for (int nj = 0; nj < 2; ++nj)
                s[mj][nj] = mfma16(ka[mj], qf[nj], zero);
        __builtin_amdgcn_s_setprio(0);

#pragma unroll
        for (int mj = 0; mj < 8; ++mj)
#pragma unroll
            for (int nj = 0; nj < 2; ++nj) {
                float p0 = __builtin_amdgcn_exp2f(s[mj][nj][0]);
                float p1 = __builtin_amdgcn_exp2f(s[mj][nj][1]);
                float p2 = __builtin_amdgcn_exp2f(s[mj][nj][2]);
                float p3 = __builtin_amdgcn_exp2f(s[mj][nj][3]);
                lsum[nj] += (p0 + p1) + (p2 + p3);
                *(uint2*)&Plds[wv][16 * nj + ll][8 * mj + 2 * hi] =
                    make_uint2(cvt_pk(p0, p1), cvt_pk(p2, p3));
            }

        // read P as B-fragments: pbf[nj][tt] = P[keys 32tt+8hi..+7][query 16nj+ll]
        bf16x8 pbf[2][4];
#pragma unroll
        for (int nj = 0; nj < 2; ++nj)
#pragma unroll
            for (int tt = 0; tt < 4; ++tt) {
                uint2 lo  = *(uint2*)&Plds[wv][16 * nj + ll][16 * tt + 4 * hi];
                uint2 hi2 = *(uint2*)&Plds[wv][16 * nj + ll][16 * tt + 4 * hi + 2];
                pbf[nj][tt] = bc8(lo.x, lo.y, hi2.x, hi2.y);
            }

        __builtin_amdgcn_s_setprio(1);
#pragma unroll
        for (int tt = 0; tt < 4; ++tt)
#pragma unroll
            for (int nj = 0; nj < 2; ++nj)
#pragma unroll
                for (int dj = 0; dj < 2; ++dj)
                    acc[nj][dj] = mfma16(va[dj][tt], pbf[nj][tt], acc[nj][dj]);
        __builtin_amdgcn_s_setprio(0);

        // E: publish-barrier, counted vmcnt (tile it+1 retired; it+2 in flight)
        asm volatile("s_waitcnt vmcnt(4)" ::: "memory");
        __builtin_amdgcn_sched_barrier(0);
        __builtin_amdgcn_s_barrier();
        cur ^= 1;
    }
    asm volatile("s_waitcnt vmcnt(0)" ::: "memory");  // retire wrapped dummy stages

#pragma unroll
    for (int nj = 0; nj < 2; ++nj) {
        lsum[nj] += __shfl_xor(lsum[nj], 16);
        lsum[nj] += __shfl_xor(lsum[nj], 32);
        float inv = 1.f / lsum[nj];
        unsigned short* ob = h2T + ((size_t)b * kL + nbase + 16 * nj + ll) * kC + h * 32;
#pragma unroll
        for (int dj = 0; dj < 2; ++dj) {
            *(uint2*)(ob + 16 * dj + 4 * hi) =
                make_uint2(cvt_pk(acc[nj][dj][0] * inv, acc[nj][dj][1] * inv),
                           cvt_pk(acc[nj][dj][2] * inv, acc[nj][dj][3] * inv));
        }
    }
}

// ---------------------------------------------------------------------------
// OUT GEMM v2 (r18, unchanged): staged-B pipeline, bias+residual, fp32 out.
// ---------------------------------------------------------------------------
__global__ __launch_bounds__(256) void out_gemm(const unsigned short* __restrict__ Wb,
                                                const unsigned short* __restrict__ h2T,
                                                const float* __restrict__ outb,
                                                const float* __restrict__ x,
                                                float* __restrict__ out) {
    __shared__ alignas(16) unsigned short Hlds[2][8][512];
    int t = threadIdx.x, wv = t >> 6, ll = t & 15, lg = (t >> 4) & 3;
    int lane = t & 63;
    int n0 = blockIdx.x * 128, o0 = blockIdx.y * 64, b = blockIdx.z;
    int obase = o0 + wv * 16;
    const unsigned short* hb = h2T + (size_t)b * kL * kC;

    bf16x8 wf[8];
#pragma unroll
    for (int k = 0; k < 8; ++k)
        wf[k] = *(const bf16x8*)(Wb + (size_t)(obase + ll) * 256 + 32 * k + 8 * lg);
    float bias[4];
#pragma unroll
    for (int r = 0; r < 4; ++r) bias[r] = outb[obase + 4 * lg + r];

    const unsigned short* hsrc0 = hb + (size_t)(n0 + 16 * (2 * wv)     + ll) * 256 + 8 * lg;
    const unsigned short* hsrc1 = hb + (size_t)(n0 + 16 * (2 * wv + 1) + ll) * 256 + 8 * lg;

    glds16(hsrc0,      &Hlds[0][2 * wv][0]);
    glds16(hsrc1,      &Hlds[0][2 * wv + 1][0]);
    glds16(hsrc0 + 32, &Hlds[1][2 * wv][0]);
    glds16(hsrc1 + 32, &Hlds[1][2 * wv + 1][0]);
    asm volatile("s_waitcnt vmcnt(2)" ::: "memory");
    __builtin_amdgcn_sched_barrier(0);
    __builtin_amdgcn_s_barrier();

    f32x4 acc[8] = {};
    int cur = 0;
    for (int c = 0; c < 8; ++c) {
        bf16x8 hf[8];
#pragma unroll
        for (int nj = 0; nj < 8; ++nj)
            hf[nj] = *(const bf16x8*)&Hlds[cur][nj][lane * 8];
        asm volatile("s_waitcnt lgkmcnt(0)" ::: "memory");
        __builtin_amdgcn_sched_barrier(0);
        __builtin_amdgcn_s_barrier();

        int kn = ((c + 2) & 7) * 32;
        glds16(hsrc0 + kn, &Hlds[cur][2 * wv][0]);
        glds16(hsrc1 + kn, &Hlds[cur][2 * wv + 1][0]);

        __builtin_amdgcn_s_setprio(1);
#pragma unroll
        for (int nj = 0; nj < 8; ++nj)
            acc[nj] = mfma16(wf[c], hf[nj], acc[nj]);
        __builtin_amdgcn_s_setprio(0);

        asm volatile("s_waitcnt vmcnt(2)" ::: "memory");
        __builtin_amdgcn_sched_barrier(0);
        __builtin_amdgcn_s_barrier();
        cur ^= 1;
    }
    asm volatile("s_waitcnt vmcnt(0)" ::: "memory");

#pragma unroll
    for (int nj = 0; nj < 8; ++nj) {
        int n = n0 + 16 * nj + ll;
#pragma unroll
        for (int r = 0; r < 4; ++r) {
            size_t row = (size_t)b * kC + obase + 4 * lg + r;
            out[row * kL + n] = acc[nj][r] + bias[r] + x[row * kL + n];
        }
    }
}

// ---------------------------------------------------------------------------
extern "C" void kernel_launch(void* const* d_in, const int* in_sizes, int n_in,
                              void* d_out, int out_size, void* d_ws, size_t ws_size,
                              hipStream_t stream) {
    const float* x     = (const float*)d_in[0];
    const float* gn_w  = (const float*)d_in[1];
    const float* gn_b  = (const float*)d_in[2];
    const float* qkv_w = (const float*)d_in[3];
    const float* qkv_b = (const float*)d_in[4];
    const float* out_w = (const float*)d_in[5];
    const float* out_b = (const float*)d_in[6];
    float* out = (float*)d_out;

    char* ws = (char*)d_ws;
    const size_t MB = 1024 * 1024;
    unsigned short* hT   = (unsigned short*)(ws);             // 0-4 MB
    unsigned short* qT   = (unsigned short*)(ws + 4  * MB);   // 4-8 MB
    unsigned short* kT   = (unsigned short*)(ws + 8  * MB);   // 8-12 MB
    unsigned short* vbuf = (unsigned short*)(ws + 12 * MB);   // 12-16 MB
    unsigned short* h2T  = (unsigned short*)(ws + 16 * MB);   // 16-20 MB
    unsigned short* wqkv = (unsigned short*)(ws + 20 * MB);   // 20-20.375 MB
    unsigned short* wout = (unsigned short*)(ws + 20 * MB + 512 * 1024);

    gncvt_kernel<<<dim3(384), 256, 0, stream>>>(x, gn_w, gn_b, hT, qkv_w, out_w, wqkv, wout);
    qkv_gemm<<<dim3(16, 12, kB), 256, 0, stream>>>(wqkv, hT, qkv_b, qT, kT, vbuf);
    attn_kernel<<<dim3(512), 256, 0, stream>>>(qT, kT, vbuf, h2T);
    out_gemm<<<dim3(16, 4, kB), 256, 0, stream>>>(wout, h2T, out_b, x, out);
}

// Round 20
// 71.344 us; speedup vs baseline: 1.3769x; 1.0277x over previous
//
#include <hip/hip_runtime.h>
#include <math.h>

using f32x4  = __attribute__((ext_vector_type(4))) float;
using bf16x8 = __attribute__((ext_vector_type(8))) short;

constexpr int kB = 4, kC = 256, kL = 2048, kH = 8;
constexpr float kQScale = 0.25505402264f;  // 1/sqrt(32) * log2(e)

__device__ __forceinline__ unsigned short f2bf(float f) {
    unsigned u = __builtin_bit_cast(unsigned, f);
    u += 0x7fffu + ((u >> 16) & 1u);
    return (unsigned short)(u >> 16);
}
__device__ __forceinline__ unsigned cvt_pk(float lo, float hi) {
    unsigned r;
    asm("v_cvt_pk_bf16_f32 %0, %1, %2" : "=v"(r) : "v"(lo), "v"(hi));
    return r;
}
__device__ __forceinline__ f32x4 mfma16(bf16x8 a, bf16x8 b, f32x4 c) {
    return __builtin_amdgcn_mfma_f32_16x16x32_bf16(a, b, c, 0, 0, 0);
}
__device__ __forceinline__ bf16x8 bc8(unsigned a, unsigned b, unsigned c, unsigned d) {
    return __builtin_bit_cast(bf16x8, make_uint4(a, b, c, d));
}
// async global->LDS, 16B per lane; LDS dest = base + lane*16 (HW-linear).
__device__ __forceinline__ void glds16(const unsigned short* g, unsigned short* l) {
    __builtin_amdgcn_global_load_lds(
        (const __attribute__((address_space(1))) unsigned int*)g,
        (__attribute__((address_space(3))) unsigned int*)l, 16, 0, 0);
}

// ---------------------------------------------------------------------------
// Fused GN (blocks 0..127) + weight cvt (blocks 128..383): one launch stage.
// ---------------------------------------------------------------------------
__global__ __launch_bounds__(256) void gncvt_kernel(const float* __restrict__ x,
                                                    const float* __restrict__ gw,
                                                    const float* __restrict__ gb,
                                                    unsigned short* __restrict__ hT,
                                                    const float* __restrict__ qkvw,
                                                    const float* __restrict__ outw,
                                                    unsigned short* __restrict__ wq,
                                                    unsigned short* __restrict__ wo) {
    if (blockIdx.x >= 128) {  // ---- cvt role ----
        int i = (blockIdx.x - 128) * 256 + threadIdx.x;  // 0..65535 float4s
        const float* s; unsigned short* d; int j;
        if (i < 49152) { s = qkvw; d = wq; j = i; }
        else           { s = outw; d = wo; j = i - 49152; }
        float4 v = ((const float4*)s)[j];
        ((uint2*)d)[j] = make_uint2(cvt_pk(v.x, v.y), cvt_pk(v.z, v.w));
        return;
    }
    // ---- groupnorm role ----
    int b = blockIdx.x >> 5, g = blockIdx.x & 31;
    int t = threadIdx.x;
    const float* xp = x + ((size_t)b * kC + g * 8) * kL + 8 * t;

    float v[8][8];
    float s = 0.f, ss = 0.f;
#pragma unroll
    for (int c = 0; c < 8; ++c) {
        float4 a  = *(const float4*)(xp + (size_t)c * kL);
        float4 a2 = *(const float4*)(xp + (size_t)c * kL + 4);
        v[c][0]=a.x; v[c][1]=a.y; v[c][2]=a.z; v[c][3]=a.w;
        v[c][4]=a2.x; v[c][5]=a2.y; v[c][6]=a2.z; v[c][7]=a2.w;
        s  += (a.x+a.y)+(a.z+a.w)+(a2.x+a2.y)+(a2.z+a2.w);
        ss += a.x*a.x+a.y*a.y+a.z*a.z+a.w*a.w+a2.x*a2.x+a2.y*a2.y+a2.z*a2.z+a2.w*a2.w;
    }
#pragma unroll
    for (int off = 32; off; off >>= 1) {
        s  += __shfl_down(s, off);
        ss += __shfl_down(ss, off);
    }
    __shared__ float red[8];
    int wv = t >> 6;
    if ((t & 63) == 0) { red[wv] = s; red[4 + wv] = ss; }
    __syncthreads();
    s  = red[0] + red[1] + red[2] + red[3];
    ss = red[4] + red[5] + red[6] + red[7];
    float mean = s * (1.f / 16384.f);
    float var  = ss * (1.f / 16384.f) - mean * mean;
    float rstd = rsqrtf(var + 1e-5f);

    float wc[8], bc[8];
#pragma unroll
    for (int c = 0; c < 8; ++c) { wc[c] = gw[g*8+c] * rstd; bc[c] = gb[g*8+c]; }

    unsigned short* hp = hT + ((size_t)b * kL + 8 * t) * kC + g * 8;
#pragma unroll
    for (int j = 0; j < 8; ++j) {
        unsigned pk[4];
#pragma unroll
        for (int c2 = 0; c2 < 4; ++c2) {
            pk[c2] = cvt_pk((v[2*c2  ][j] - mean) * wc[2*c2  ] + bc[2*c2  ],
                            (v[2*c2+1][j] - mean) * wc[2*c2+1] + bc[2*c2+1]);
        }
        *(uint4*)(hp + (size_t)j * kC) = make_uint4(pk[0], pk[1], pk[2], pk[3]);
    }
}

// ---------------------------------------------------------------------------
// Merged QKV GEMM v2 (r18, unchanged): W-in-registers + LDS-staged B shared by
// all 4 waves, counted-vmcnt barriers.
// ---------------------------------------------------------------------------
__device__ __forceinline__ void store_qk(unsigned short* __restrict__ base, size_t bh,
                                         int n, int d0, f32x4 acc,
                                         const float* bias4, float scale) {
    float v0 = (acc[0] + bias4[0]) * scale, v1 = (acc[1] + bias4[1]) * scale;
    float v2 = (acc[2] + bias4[2]) * scale, v3 = (acc[3] + bias4[3]) * scale;
    *(uint2*)(base + (bh * kL + n) * 32 + d0) = make_uint2(cvt_pk(v0, v1), cvt_pk(v2, v3));
}

__global__ __launch_bounds__(256) void qkv_gemm(const unsigned short* __restrict__ Wb,
                                                const unsigned short* __restrict__ hT,
                                                const float* __restrict__ qkvb,
                                                unsigned short* __restrict__ qT,
                                                unsigned short* __restrict__ kT,
                                                unsigned short* __restrict__ vbuf) {
    __shared__ alignas(16) unsigned short Hlds[2][8][512];
    int t = threadIdx.x, wv = t >> 6, ll = t & 15, lg = (t >> 4) & 3;
    int lane = t & 63;
    int n0 = blockIdx.x * 128, o0 = blockIdx.y * 64, b = blockIdx.z;
    int obase = o0 + wv * 16;
    const unsigned short* hb = hT + (size_t)b * kL * kC;

    bf16x8 wf[8];
#pragma unroll
    for (int k = 0; k < 8; ++k)
        wf[k] = *(const bf16x8*)(Wb + (size_t)(obase + ll) * 256 + 32 * k + 8 * lg);
    float bias[4];
#pragma unroll
    for (int r = 0; r < 4; ++r) bias[r] = qkvb[obase + 4 * lg + r];
    int mode = (obase < 256) ? 0 : (obase < 512 ? 1 : 2);
    int d0 = (obase & 31) + 4 * lg;

    const unsigned short* hsrc0 = hb + (size_t)(n0 + 16 * (2 * wv)     + ll) * 256 + 8 * lg;
    const unsigned short* hsrc1 = hb + (size_t)(n0 + 16 * (2 * wv + 1) + ll) * 256 + 8 * lg;

    glds16(hsrc0,      &Hlds[0][2 * wv][0]);
    glds16(hsrc1,      &Hlds[0][2 * wv + 1][0]);
    glds16(hsrc0 + 32, &Hlds[1][2 * wv][0]);
    glds16(hsrc1 + 32, &Hlds[1][2 * wv + 1][0]);
    asm volatile("s_waitcnt vmcnt(2)" ::: "memory");
    __builtin_amdgcn_sched_barrier(0);
    __builtin_amdgcn_s_barrier();

    f32x4 acc[8] = {};
    int cur = 0;
    for (int c = 0; c < 8; ++c) {
        bf16x8 hf[8];
#pragma unroll
        for (int nj = 0; nj < 8; ++nj)
            hf[nj] = *(const bf16x8*)&Hlds[cur][nj][lane * 8];
        asm volatile("s_waitcnt lgkmcnt(0)" ::: "memory");
        __builtin_amdgcn_sched_barrier(0);
        __builtin_amdgcn_s_barrier();

        int kn = ((c + 2) & 7) * 32;
        glds16(hsrc0 + kn, &Hlds[cur][2 * wv][0]);
        glds16(hsrc1 + kn, &Hlds[cur][2 * wv + 1][0]);

        __builtin_amdgcn_s_setprio(1);
#pragma unroll
        for (int nj = 0; nj < 8; ++nj)
            acc[nj] = mfma16(wf[c], hf[nj], acc[nj]);
        __builtin_amdgcn_s_setprio(0);

        asm volatile("s_waitcnt vmcnt(2)" ::: "memory");
        __builtin_amdgcn_sched_barrier(0);
        __builtin_amdgcn_s_barrier();
        cur ^= 1;
    }
    asm volatile("s_waitcnt vmcnt(0)" ::: "memory");

#pragma unroll
    for (int nj = 0; nj < 8; ++nj) {
        int n = n0 + 16 * nj + ll;
        if (mode == 0) {
            store_qk(qT, (size_t)b * kH + (obase >> 5), n, d0, acc[nj], bias, kQScale);
        } else if (mode == 1) {
            store_qk(kT, (size_t)b * kH + ((obase - 256) >> 5), n, d0, acc[nj], bias, 1.f);
        } else {
#pragma unroll
            for (int r = 0; r < 4; ++r) {
                size_t row = (size_t)b * kC + (obase - 512) + 4 * lg + r;
                vbuf[row * kL + n] = f2bf(acc[nj][r] + bias[r]);
            }
        }
    }
}

// ---------------------------------------------------------------------------
// Flash attention v20 = r17 counted-vmcnt structure at DOUBLE block residency:
// 16 q/wave, 64-q blocks -> grid 1024 = 4 blocks/CU (16 waves/CU), tail-free.
// 64-key tiles; LDS = K 8KB + V 8KB + Plds[4][16][34] 8.7KB = 24.7KB.
// Per wave per tile: 1 K glds + 1 V glds (counted vmcnt(2)); 4 QK MFMA,
// 32 exp2, 4 PV MFMA. Per-query arithmetic (key order, lsum add order,
// PV tt-order, shfl reduce) = r17/r19 verbatim -> absmax 0.03125.
// ---------------------------------------------------------------------------
__global__ __launch_bounds__(256) void attn_kernel(const unsigned short* __restrict__ qT,
                                                   const unsigned short* __restrict__ kT,
                                                   const unsigned short* __restrict__ vbuf,
                                                   unsigned short* __restrict__ h2T) {
    __shared__ alignas(16) unsigned short Klds[2][4][512];  // [buf][mj][frag order]
    __shared__ alignas(16) unsigned short Vlds[2][4][512];  // [buf][dj*2+tt][frag]
    __shared__ unsigned Plds[4][16][34];
    int t = threadIdx.x, wv = t >> 6, ll = t & 15, hi = (t >> 4) & 3;
    int lane = t & 63;
    int j = blockIdx.x;
    int bid = (j & 7) * 128 + (j >> 3);   // XCD swizzle: 1024 = 8 x 128, bijective
    int qg = bid & 31, bh = bid >> 5;     // qg 0..31 (64-q groups), bh 0..31
    int b = bh >> 3, h = bh & 7;
    const unsigned short* qb = qT + (size_t)bh * kL * 32;
    const unsigned short* kb = kT + (size_t)bh * kL * 32;
    const unsigned short* vb = vbuf + ((size_t)b * kC + h * 32) * kL;
    int nq = qg * 64 + wv * 16;           // this wave's 16 queries

    bf16x8 qf = *(const bf16x8*)(qb + (size_t)(nq + ll) * 32 + 8 * hi);

    f32x4 acc[2] = {};                    // [dj]
    float lsum = 0.f;
    const f32x4 zero = {0.f, 0.f, 0.f, 0.f};

    // staging assignments: wave stages K sub-tile mj=wv and V sub-tile
    // (dj,tt) = (wv>>1, wv&1); 1KB wave-wide glds16 each.
    const unsigned short* ksrc = kb + (size_t)(16 * wv + ll) * 32 + 8 * hi;
    const unsigned short* vsrc = vb + (size_t)(16 * (wv >> 1) + ll) * kL + 32 * (wv & 1) + 8 * hi;

    // prologue: stage tiles 0 and 1
    glds16(ksrc, &Klds[0][wv][0]);
    glds16(vsrc, &Vlds[0][wv][0]);
    glds16(ksrc + (size_t)64 * 32, &Klds[1][wv][0]);
    glds16(vsrc + 64,              &Vlds[1][wv][0]);
    asm volatile("s_waitcnt vmcnt(2)" ::: "memory");
    __builtin_amdgcn_sched_barrier(0);
    __builtin_amdgcn_s_barrier();

    int cur = 0;
    for (int it = 0; it < 32; ++it) {
        // A: read tile-it fragments (conflict-free b128)
        bf16x8 ka[4], va[2][2];
#pragma unroll
        for (int mj = 0; mj < 4; ++mj)
            ka[mj] = *(const bf16x8*)&Klds[cur][mj][lane * 8];
#pragma unroll
        for (int dj = 0; dj < 2; ++dj)
#pragma unroll
            for (int tt = 0; tt < 2; ++tt)
                va[dj][tt] = *(const bf16x8*)&Vlds[cur][dj * 2 + tt][lane * 8];

        // B: read-barrier -> buf[cur] may be overwritten
        asm volatile("s_waitcnt lgkmcnt(0)" ::: "memory");
        __builtin_amdgcn_sched_barrier(0);
        __builtin_amdgcn_s_barrier();

        // C: stage tile it+2 into buf[cur] (wraps harmlessly on last 2 iters)
        int kn = ((it + 2) & 31) * 64;
        glds16(ksrc + (size_t)kn * 32, &Klds[cur][wv][0]);
        glds16(vsrc + kn,              &Vlds[cur][wv][0]);

        // D: compute — QK^T: s[mj] = S^T[key 64it+16mj+4hi+r][query nq+ll]
        f32x4 s[4];
        __builtin_amdgcn_s_setprio(1);
#pragma unroll
        for (int mj = 0; mj < 4; ++mj)
            s[mj] = mfma16(ka[mj], qf, zero);
        __builtin_amdgcn_s_setprio(0);

#pragma unroll
        for (int mj = 0; mj < 4; ++mj) {
            float p0 = __builtin_amdgcn_exp2f(s[mj][0]);
            float p1 = __builtin_amdgcn_exp2f(s[mj][1]);
            float p2 = __builtin_amdgcn_exp2f(s[mj][2]);
            float p3 = __builtin_amdgcn_exp2f(s[mj][3]);
            lsum += (p0 + p1) + (p2 + p3);
            *(uint2*)&Plds[wv][ll][8 * mj + 2 * hi] =
                make_uint2(cvt_pk(p0, p1), cvt_pk(p2, p3));
        }

        // read P as B-fragments: pbf[tt] = P[keys 32tt+8hi..+7][query ll]
        bf16x8 pbf[2];
#pragma unroll
        for (int tt = 0; tt < 2; ++tt) {
            uint2 lo  = *(uint2*)&Plds[wv][ll][16 * tt + 4 * hi];
            uint2 hi2 = *(uint2*)&Plds[wv][ll][16 * tt + 4 * hi + 2];
            pbf[tt] = bc8(lo.x, lo.y, hi2.x, hi2.y);
        }

        __builtin_amdgcn_s_setprio(1);
#pragma unroll
        for (int tt = 0; tt < 2; ++tt)
#pragma unroll
            for (int dj = 0; dj < 2; ++dj)
                acc[dj] = mfma16(va[dj][tt], pbf[tt], acc[dj]);
        __builtin_amdgcn_s_setprio(0);

        // E: publish-barrier, counted vmcnt (tile it+1 retired; it+2 in flight)
        asm volatile("s_waitcnt vmcnt(2)" ::: "memory");
        __builtin_amdgcn_sched_barrier(0);
        __builtin_amdgcn_s_barrier();
        cur ^= 1;
    }
    asm volatile("s_waitcnt vmcnt(0)" ::: "memory");  // retire wrapped dummy stages

    lsum += __shfl_xor(lsum, 16);
    lsum += __shfl_xor(lsum, 32);
    float inv = 1.f / lsum;
    unsigned short* ob = h2T + ((size_t)b * kL + nq + ll) * kC + h * 32;
    *(uint2*)(ob + 4 * hi)      = make_uint2(cvt_pk(acc[0][0] * inv, acc[0][1] * inv),
                                             cvt_pk(acc[0][2] * inv, acc[0][3] * inv));
    *(uint2*)(ob + 16 + 4 * hi) = make_uint2(cvt_pk(acc[1][0] * inv, acc[1][1] * inv),
                                             cvt_pk(acc[1][2] * inv, acc[1][3] * inv));
}

// ---------------------------------------------------------------------------
// OUT GEMM v2 (r18, unchanged): staged-B pipeline, bias+residual, fp32 out.
// ---------------------------------------------------------------------------
__global__ __launch_bounds__(256) void out_gemm(const unsigned short* __restrict__ Wb,
                                                const unsigned short* __restrict__ h2T,
                                                const float* __restrict__ outb,
                                                const float* __restrict__ x,
                                                float* __restrict__ out) {
    __shared__ alignas(16) unsigned short Hlds[2][8][512];
    int t = threadIdx.x, wv = t >> 6, ll = t & 15, lg = (t >> 4) & 3;
    int lane = t & 63;
    int n0 = blockIdx.x * 128, o0 = blockIdx.y * 64, b = blockIdx.z;
    int obase = o0 + wv * 16;
    const unsigned short* hb = h2T + (size_t)b * kL * kC;

    bf16x8 wf[8];
#pragma unroll
    for (int k = 0; k < 8; ++k)
        wf[k] = *(const bf16x8*)(Wb + (size_t)(obase + ll) * 256 + 32 * k + 8 * lg);
    float bias[4];
#pragma unroll
    for (int r = 0; r < 4; ++r) bias[r] = outb[obase + 4 * lg + r];

    const unsigned short* hsrc0 = hb + (size_t)(n0 + 16 * (2 * wv)     + ll) * 256 + 8 * lg;
    const unsigned short* hsrc1 = hb + (size_t)(n0 + 16 * (2 * wv + 1) + ll) * 256 + 8 * lg;

    glds16(hsrc0,      &Hlds[0][2 * wv][0]);
    glds16(hsrc1,      &Hlds[0][2 * wv + 1][0]);
    glds16(hsrc0 + 32, &Hlds[1][2 * wv][0]);
    glds16(hsrc1 + 32, &Hlds[1][2 * wv + 1][0]);
    asm volatile("s_waitcnt vmcnt(2)" ::: "memory");
    __builtin_amdgcn_sched_barrier(0);
    __builtin_amdgcn_s_barrier();

    f32x4 acc[8] = {};
    int cur = 0;
    for (int c = 0; c < 8; ++c) {
        bf16x8 hf[8];
#pragma unroll
        for (int nj = 0; nj < 8; ++nj)
            hf[nj] = *(const bf16x8*)&Hlds[cur][nj][lane * 8];
        asm volatile("s_waitcnt lgkmcnt(0)" ::: "memory");
        __builtin_amdgcn_sched_barrier(0);
        __builtin_amdgcn_s_barrier();

        int kn = ((c + 2) & 7) * 32;
        glds16(hsrc0 + kn, &Hlds[cur][2 * wv][0]);
        glds16(hsrc1 + kn, &Hlds[cur][2 * wv + 1][0]);

        __builtin_amdgcn_s_setprio(1);
#pragma unroll
        for (int nj = 0; nj < 8; ++nj)
            acc[nj] = mfma16(wf[c], hf[nj], acc[nj]);
        __builtin_amdgcn_s_setprio(0);

        asm volatile("s_waitcnt vmcnt(2)" ::: "memory");
        __builtin_amdgcn_sched_barrier(0);
        __builtin_amdgcn_s_barrier();
        cur ^= 1;
    }
    asm volatile("s_waitcnt vmcnt(0)" ::: "memory");

#pragma unroll
    for (int nj = 0; nj < 8; ++nj) {
        int n = n0 + 16 * nj + ll;
#pragma unroll
        for (int r = 0; r < 4; ++r) {
            size_t row = (size_t)b * kC + obase + 4 * lg + r;
            out[row * kL + n] = acc[nj][r] + bias[r] + x[row * kL + n];
        }
    }
}

// ---------------------------------------------------------------------------
extern "C" void kernel_launch(void* const* d_in, const int* in_sizes, int n_in,
                              void* d_out, int out_size, void* d_ws, size_t ws_size,
                              hipStream_t stream) {
    const float* x     = (const float*)d_in[0];
    const float* gn_w  = (const float*)d_in[1];
    const float* gn_b  = (const float*)d_in[2];
    const float* qkv_w = (const float*)d_in[3];
    const float* qkv_b = (const float*)d_in[4];
    const float* out_w = (const float*)d_in[5];
    const float* out_b = (const float*)d_in[6];
    float* out = (float*)d_out;

    char* ws = (char*)d_ws;
    const size_t MB = 1024 * 1024;
    unsigned short* hT   = (unsigned short*)(ws);             // 0-4 MB
    unsigned short* qT   = (unsigned short*)(ws + 4  * MB);   // 4-8 MB
    unsigned short* kT   = (unsigned short*)(ws + 8  * MB);   // 8-12 MB
    unsigned short* vbuf = (unsigned short*)(ws + 12 * MB);   // 12-16 MB
    unsigned short* h2T  = (unsigned short*)(ws + 16 * MB);   // 16-20 MB
    unsigned short* wqkv = (unsigned short*)(ws + 20 * MB);   // 20-20.375 MB
    unsigned short* wout = (unsigned short*)(ws + 20 * MB + 512 * 1024);

    gncvt_kernel<<<dim3(384), 256, 0, stream>>>(x, gn_w, gn_b, hT, qkv_w, out_w, wqkv, wout);
    qkv_gemm<<<dim3(16, 12, kB), 256, 0, stream>>>(wqkv, hT, qkv_b, qT, kT, vbuf);
    attn_kernel<<<dim3(1024), 256, 0, stream>>>(qT, kT, vbuf, h2T);
    out_gemm<<<dim3(16, 4, kB), 256, 0, stream>>>(wout, h2T, out_b, x, out);
}